// Round 3
// baseline (2560.382 us; speedup 1.0000x reference)
//
#include <hip/hip_runtime.h>

#define NN 50000
#define NE 800000
#define DIN 32
#define DD 96
#define NL 4
#define NCLS 10
#define EPSF 1e-6f

typedef unsigned short u16;
typedef unsigned int u32;

typedef __bf16 bf16x8 __attribute__((ext_vector_type(8)));
typedef float f32x4 __attribute__((ext_vector_type(4)));

static __device__ __forceinline__ u16 f2bf(float f) {
    u32 x = __float_as_uint(f);
    x += 0x7FFFu + ((x >> 16) & 1u);   // round-to-nearest-even
    return (u16)(x >> 16);
}
// packed RNE f32x2 -> bf16x2 in one instruction (gfx950)
static __device__ __forceinline__ u32 pk2(float a, float b) {
    u32 r;
    asm("v_cvt_pk_bf16_f32 %0, %1, %2" : "=v"(r) : "v"(a), "v"(b));
    return r;
}
static __device__ __forceinline__ float unlo(u32 u) { return __uint_as_float(u << 16); }
static __device__ __forceinline__ float unhi(u32 u) { return __uint_as_float(u & 0xFFFF0000u); }
static __device__ __forceinline__ float frcp(float x) { return __builtin_amdgcn_rcpf(x); }

__global__ void k_zero4(int* __restrict__ p, long n4) {
    long i = (long)blockIdx.x * blockDim.x + threadIdx.x;
    if (i < n4) ((int4*)p)[i] = make_int4(0, 0, 0, 0);
}

__global__ void k_hist(const int* __restrict__ dst, int* __restrict__ counts) {
    int i = blockIdx.x * blockDim.x + threadIdx.x;
    if (i < NE) atomicAdd(&counts[dst[i]], 1);
}

// multi-block scan, pass 1: per-block local exclusive scan + block sums
__global__ __launch_bounds__(1024) void k_scan1(const int* __restrict__ counts,
                                                int* __restrict__ excl,
                                                int* __restrict__ bsum, int n) {
    __shared__ int wsum[16];
    const int tid = threadIdx.x, lane = tid & 63, wid = tid >> 6;
    const int i = blockIdx.x * 1024 + tid;
    int v = (i < n) ? counts[i] : 0;
    int x = v;
#pragma unroll
    for (int off = 1; off < 64; off <<= 1) {
        int t = __shfl_up(x, (unsigned)off, 64);
        if (lane >= off) x += t;
    }
    if (lane == 63) wsum[wid] = x;
    __syncthreads();
    if (tid < 16) {
        int s = wsum[tid];
#pragma unroll
        for (int off = 1; off < 16; off <<= 1) {
            int t = __shfl_up(s, (unsigned)off, 16);
            if (tid >= off) s += t;
        }
        wsum[tid] = s;
    }
    __syncthreads();
    const int wbase = wid ? wsum[wid - 1] : 0;
    if (i < n) excl[i] = wbase + x - v;
    if (tid == 1023) bsum[blockIdx.x] = wbase + x;
}

// pass 2: exclusive scan of block sums (<=64 blocks), single wave
__global__ void k_scan2(int* __restrict__ bsum, int nb) {
    const int lane = threadIdx.x;
    int v = (lane < nb) ? bsum[lane] : 0;
    int x = v;
#pragma unroll
    for (int off = 1; off < 64; off <<= 1) {
        int t = __shfl_up(x, (unsigned)off, 64);
        if (lane >= off) x += t;
    }
    if (lane < nb) bsum[lane] = x - v;
}

// pass 3: add block offsets -> final row_ptr and cursor copy; row_ptr[n]=NE.
__global__ void k_scan3(int* __restrict__ row_ptr, int* __restrict__ cursor,
                        const int* __restrict__ bsum, int n) {
    int i = blockIdx.x * blockDim.x + threadIdx.x;
    if (i < n) {
        int v = row_ptr[i] + bsum[i >> 10];
        row_ptr[i] = v;
        cursor[i] = v;
    }
    if (i == 0) row_ptr[n] = NE;
}

__global__ void k_scatter(const int* __restrict__ src, const int* __restrict__ dst,
                          int* __restrict__ cursor, int* __restrict__ eperm,
                          int* __restrict__ srcp) {
    int i = blockIdx.x * blockDim.x + threadIdx.x;
    if (i >= NE) return;
    int pos = atomicAdd(&cursor[dst[i]], 1);
    eperm[pos] = i;
    srcp[pos] = src[i];
}

// Fused packer: 5x [NL][96][96] layer weights (all k-permuted: both h-state and
// e-state live in the permuted basis), 2x [32,96] projections (canonical k),
// and the permuted-row copy of mlp0_w.
__global__ void k_packAll(const float* __restrict__ A_w, const float* __restrict__ B_w,
                          const float* __restrict__ C_w, const float* __restrict__ D_w,
                          const float* __restrict__ E_w,
                          const float* __restrict__ fp_w, const float* __restrict__ ep_w,
                          const float* __restrict__ m0w,
                          u16* __restrict__ awf, u16* __restrict__ bwf, u16* __restrict__ cwf,
                          u16* __restrict__ dwf, u16* __restrict__ ewf,
                          u16* __restrict__ wfp, u16* __restrict__ wep,
                          float* __restrict__ w0p) {
    const int PER = NL * 6 * 3 * 64;   // 4608 fragments per tensor
    int q = blockIdx.x * blockDim.x + threadIdx.x;
    if (q < 5 * PER) {
        int which = q / PER;
        int qq = q - which * PER;
        const float* W_all = which == 0 ? A_w : which == 1 ? B_w : which == 2 ? C_w
                           : which == 3 ? D_w : E_w;
        u16* wf = which == 0 ? awf : which == 1 ? bwf : which == 2 ? cwf
                : which == 3 ? dwf : ewf;
        int l = qq / (6 * 3 * 64);
        int rem = qq - l * (6 * 3 * 64);
        int tile = rem / (3 * 64);
        int rem2 = rem - tile * (3 * 64);
        int c = rem2 >> 6, ln = rem2 & 63;
        const float* W = W_all + (long)l * DD * DD;
        int n = tile * 16 + (ln & 15);
        int k0 = c * 32 + (ln >> 4) * 8;
        u16 wv[8];
#pragma unroll
        for (int j = 0; j < 8; ++j) {
            int kk = k0 + j;
            int kact = (kk % 6) * 16 + kk / 6;   // stored-p -> actual feature
            wv[j] = f2bf(W[kact * DD + n]);
        }
        *(uint4*)&wf[(long)qq * 8] = *(uint4*)wv;
    } else if (q < 5 * PER + 768) {
        int qq = q - 5 * PER;
        int which = qq / 384; qq -= which * 384;
        const float* W = which ? ep_w : fp_w;
        u16* wf = which ? wep : wfp;
        int ln = qq & 63;
        int n = (qq >> 6) * 16 + (ln & 15);
        int k0 = (ln >> 4) * 8;
        u16 wv[8];
#pragma unroll
        for (int j = 0; j < 8; ++j) wv[j] = f2bf(W[(k0 + j) * DD + n]);
        *(uint4*)&wf[qq * 8] = *(uint4*)wv;
    } else {
        int qq = q - 5 * PER - 768;
        if (qq < DD * 48) {
            int p = qq / 48, j = qq - p * 48;
            int jp = (p % 6) * 16 + p / 6;       // actual feature of stored p
            w0p[qq] = m0w[jp * 48 + j];
        }
    }
}

// Barrier-free MFMA input projection: one wave per 16-row tile, grid-stride.
// POUT: permuted-basis output (stored p = lm*6+t holds actual col t*16+lm).
// BFOUT selects bf16 (3x u32) vs f32 (3x float2) stores on the POUT path.
template <bool BFOUT, bool PERM, bool POUT>
__global__ __launch_bounds__(256) void k_proj_m(const float* __restrict__ X,
                                                const u16* __restrict__ wf,
                                                const float* __restrict__ B,
                                                void* __restrict__ Y,
                                                const int* __restrict__ eperm,
                                                int ntiles) {
    const int lane = threadIdx.x & 63;
    const int gw = (blockIdx.x * blockDim.x + threadIdx.x) >> 6;
    const int nw = (gridDim.x * blockDim.x) >> 6;
    const int lm = lane & 15, quad = lane >> 4;

    bf16x8 bfr[6];
    float bias[6];
#pragma unroll
    for (int t = 0; t < 6; ++t) {
        bfr[t] = *(const bf16x8*)&wf[(t * 64 + lane) * 8];
        bias[t] = B[t * 16 + lm];
    }

    for (int tile = gw; tile < ntiles; tile += nw) {
        const int row = tile * 16 + lm;
        const long srow = PERM ? (long)eperm[row] : (long)row;
        float4 x0 = *(const float4*)&X[srow * DIN + quad * 8];
        float4 x1 = *(const float4*)&X[srow * DIN + quad * 8 + 4];
        u32 ap[4] = {pk2(x0.x, x0.y), pk2(x0.z, x0.w), pk2(x1.x, x1.y), pk2(x1.z, x1.w)};
        bf16x8 af = *(bf16x8*)ap;
        f32x4 acc[6];
#pragma unroll
        for (int t = 0; t < 6; ++t) {
            acc[t] = (f32x4){bias[t], bias[t], bias[t], bias[t]};
            acc[t] = __builtin_amdgcn_mfma_f32_16x16x32_bf16(af, bfr[t], acc[t], 0, 0, 0);
        }
        const long rbase = (long)tile * 16 + quad * 4;
        if (POUT) {
#pragma unroll
            for (int r = 0; r < 4; ++r) {
                if (BFOUT) {
                    u16* p = (u16*)Y + (rbase + r) * DD + lm * 6;
                    *(u32*)p       = pk2(acc[0][r], acc[1][r]);
                    *(u32*)(p + 2) = pk2(acc[2][r], acc[3][r]);
                    *(u32*)(p + 4) = pk2(acc[4][r], acc[5][r]);
                } else {
                    float* p = (float*)Y + (rbase + r) * DD + lm * 6;
                    *(float2*)(p)     = make_float2(acc[0][r], acc[1][r]);
                    *(float2*)(p + 2) = make_float2(acc[2][r], acc[3][r]);
                    *(float2*)(p + 4) = make_float2(acc[4][r], acc[5][r]);
                }
            }
        } else {
#pragma unroll
            for (int t = 0; t < 6; ++t) {
                const int j = t * 16 + lm;
#pragma unroll
                for (int r = 0; r < 4; ++r) {
                    float v = acc[t][r];
                    if (BFOUT) ((u16*)Y)[(rbase + r) * DD + j] = f2bf(v);
                    else       ((float*)Y)[(rbase + r) * DD + j] = v;
                }
            }
        }
    }
}

// Barrier-free MFMA 4-way node GEMM: wave w of each block handles matrix w.
// All outputs in permuted basis: A -> f32 (3x float2), B/D/E -> bf16 (3x u32).
__global__ __launch_bounds__(256) void k_gemm4m(const float* __restrict__ X,
                                                const u16* __restrict__ awf, const float* __restrict__ ab,
                                                const u16* __restrict__ bwf, const float* __restrict__ bb,
                                                const u16* __restrict__ dwf, const float* __restrict__ db,
                                                const u16* __restrict__ ewf, const float* __restrict__ eb,
                                                float* __restrict__ Y0, u16* __restrict__ Y1,
                                                u16* __restrict__ Y2, u16* __restrict__ Y3,
                                                int ntiles) {
    const int lane = threadIdx.x & 63;
    const int w = threadIdx.x >> 6;   // matrix 0..3
    const int lm = lane & 15, quad = lane >> 4;
    const u16* wf = (w == 0) ? awf : (w == 1) ? bwf : (w == 2) ? dwf : ewf;
    const float* bp = (w == 0) ? ab : (w == 1) ? bb : (w == 2) ? db : eb;

    bf16x8 bfr[6][3];
    float bias[6];
#pragma unroll
    for (int t = 0; t < 6; ++t) {
#pragma unroll
        for (int c = 0; c < 3; ++c)
            bfr[t][c] = *(const bf16x8*)&wf[((t * 3 + c) * 64 + lane) * 8];
        bias[t] = bp[t * 16 + lm];
    }

    for (int tile = blockIdx.x; tile < ntiles; tile += gridDim.x) {
        const float* xr = X + (long)(tile * 16 + lm) * DD;
        bf16x8 a[3];
#pragma unroll
        for (int c = 0; c < 3; ++c) {
            float4 x0 = *(const float4*)&xr[c * 32 + quad * 8];
            float4 x1 = *(const float4*)&xr[c * 32 + quad * 8 + 4];
            u32 ap[4] = {pk2(x0.x, x0.y), pk2(x0.z, x0.w), pk2(x1.x, x1.y), pk2(x1.z, x1.w)};
            a[c] = *(bf16x8*)ap;
        }
        f32x4 acc[6];
#pragma unroll
        for (int t = 0; t < 6; ++t) {
            acc[t] = (f32x4){bias[t], bias[t], bias[t], bias[t]};
#pragma unroll
            for (int c = 0; c < 3; ++c)
                acc[t] = __builtin_amdgcn_mfma_f32_16x16x32_bf16(a[c], bfr[t][c], acc[t], 0, 0, 0);
        }
        const long rbase = (long)tile * 16 + quad * 4;
        if (w == 0) {
#pragma unroll
            for (int r = 0; r < 4; ++r) {
                float* p = Y0 + (rbase + r) * DD + lm * 6;
                *(float2*)(p)     = make_float2(acc[0][r], acc[1][r]);
                *(float2*)(p + 2) = make_float2(acc[2][r], acc[3][r]);
                *(float2*)(p + 4) = make_float2(acc[4][r], acc[5][r]);
            }
        } else {
            u16* Yp = (w == 1) ? Y1 : (w == 2) ? Y2 : Y3;
#pragma unroll
            for (int r = 0; r < 4; ++r) {
                u16* p = Yp + (rbase + r) * DD + lm * 6;
                *(u32*)p       = pk2(acc[0][r], acc[1][r]);
                *(u32*)(p + 2) = pk2(acc[2][r], acc[3][r]);
                *(u32*)(p + 4) = pk2(acc[4][r], acc[5][r]);
            }
        }
    }
}

// Barrier-free (post-stage), LDS-staged-weights, atomic-free fused edge+aggregate.
// One wave per node (grid-stride). C-weight fragments live in LDS (shared by
// the block's 4 waves) -> ~72 fewer VGPRs/wave -> higher residency.
// Cross-node pipelining: next node's row_ptr prefetched at node top (uniform
// s_loads); next node's first A-chunk prefetched at this node's last chunk
// (disjoint edge rows -> race-free), tracked by pref_node.
__global__ __launch_bounds__(256, 4) void k_node_edge_w(u16* ebuf,
                                                        const u16* __restrict__ cwf,  // k-permuted pack
                                                        const float* __restrict__ Cb,
                                                        const u16* __restrict__ Dh,
                                                        const u16* __restrict__ Eh,
                                                        const u16* __restrict__ Bh,
                                                        const int* __restrict__ srcp,
                                                        const int* __restrict__ row_ptr,
                                                        const float* __restrict__ Ah,
                                                        float* __restrict__ hbuf) {
    __shared__ u16 cw_lds[6 * 3 * 64 * 8];   // 18432 B
    const int lane = threadIdx.x & 63;
    const int gw = (blockIdx.x * blockDim.x + threadIdx.x) >> 6;
    const int nw = (gridDim.x * blockDim.x) >> 6;
    const int lm = lane & 15, quad = lane >> 4;

    for (int idx = threadIdx.x; idx < 6 * 3 * 64; idx += 256)
        ((uint4*)cw_lds)[idx] = ((const uint4*)cwf)[idx];
    __syncthreads();

    float cb[6];
#pragma unroll
    for (int t = 0; t < 6; ++t) cb[t] = Cb[t * 16 + lm];   // stored p=lm*6+t

    int n = gw;
    int nr0 = 0, nr1 = 0;
    if (n < NN) { nr0 = row_ptr[n]; nr1 = row_ptr[n + 1]; }
    int pref_node = -1;
    bf16x8 a[3];

    while (n < NN) {
        const int r0 = nr0, r1 = nr1;
        const int n2 = n + nw;
        if (n2 < NN) { nr0 = row_ptr[n2]; nr1 = row_ptr[n2 + 1]; }

        float nacc[6] = {0.f, 0.f, 0.f, 0.f, 0.f, 0.f};
        float dacc[6] = {0.f, 0.f, 0.f, 0.f, 0.f, 0.f};

        if (r0 < r1) {
            float eh[6];
            {
                const u16* ep = Eh + (long)n * DD + lm * 6;
                u32 e0 = *(const u32*)ep, e1 = *(const u32*)(ep + 2), e2 = *(const u32*)(ep + 4);
                eh[0] = unlo(e0); eh[1] = unhi(e0); eh[2] = unlo(e1);
                eh[3] = unhi(e1); eh[4] = unlo(e2); eh[5] = unhi(e2);
            }
            if (pref_node != n) {
                const int rows = r1 - r0 < 16 ? r1 - r0 : 16;
                const long arow = r0 + (lm < rows ? lm : 0);
#pragma unroll
                for (int c = 0; c < 3; ++c)
                    a[c] = *(const bf16x8*)&ebuf[arow * DD + c * 32 + quad * 8];
            }

            for (int chunk = r0; chunk < r1; chunk += 16) {
                const int rows = r1 - chunk < 16 ? r1 - chunk : 16;
                int sr[4];
#pragma unroll
                for (int r = 0; r < 4; ++r) {
                    int rl = quad * 4 + r;
                    sr[r] = (chunk + rl < r1) ? srcp[chunk + rl] : 0;
                }
                f32x4 acc[6];
#pragma unroll
                for (int t = 0; t < 6; ++t)
                    acc[t] = (f32x4){cb[t], cb[t], cb[t], cb[t]};
#pragma unroll
                for (int c = 0; c < 3; ++c) {
#pragma unroll
                    for (int t = 0; t < 6; ++t) {
                        const bf16x8 bw = *(const bf16x8*)&cw_lds[((t * 3 + c) * 64 + lane) * 8];
                        acc[t] = __builtin_amdgcn_mfma_f32_16x16x32_bf16(a[c], bw, acc[t], 0, 0, 0);
                    }
                }
                // prefetch next chunk (this node) or next node's first chunk
                const int nchunk = chunk + 16;
                if (nchunk < r1) {
                    const int rows2 = r1 - nchunk < 16 ? r1 - nchunk : 16;
                    const long arow2 = nchunk + (lm < rows2 ? lm : 0);
#pragma unroll
                    for (int c = 0; c < 3; ++c)
                        a[c] = *(const bf16x8*)&ebuf[arow2 * DD + c * 32 + quad * 8];
                } else if (n2 < NN && nr0 < nr1) {
                    const int rows2 = nr1 - nr0 < 16 ? nr1 - nr0 : 16;
                    const long arow2 = nr0 + (lm < rows2 ? lm : 0);
#pragma unroll
                    for (int c = 0; c < 3; ++c)
                        a[c] = *(const bf16x8*)&ebuf[arow2 * DD + c * 32 + quad * 8];
                    pref_node = n2;
                }
                // epilogue: row = quad*4+r; lane owns stored cols lm*6..lm*6+5
#pragma unroll
                for (int r = 0; r < 4; ++r) {
                    const int rl = quad * 4 + r;
                    if (rl < rows) {
                        const long s = sr[r];
                        const u16* dp = Dh + s * DD + lm * 6;
                        const u16* bp = Bh + s * DD + lm * 6;
                        u16* ep = ebuf + (long)(chunk + rl) * DD + lm * 6;
                        u32 d0 = *(const u32*)dp, d1 = *(const u32*)(dp + 2), d2 = *(const u32*)(dp + 4);
                        u32 b0 = *(const u32*)bp, b1 = *(const u32*)(bp + 2), b2 = *(const u32*)(bp + 4);
                        u32 o0 = *(const u32*)ep, o1 = *(const u32*)(ep + 2), o2 = *(const u32*)(ep + 4);
                        float dh[6] = {unlo(d0), unhi(d0), unlo(d1), unhi(d1), unlo(d2), unhi(d2)};
                        float bh[6] = {unlo(b0), unhi(b0), unlo(b1), unhi(b1), unlo(b2), unhi(b2)};
                        float od[6] = {unlo(o0), unhi(o0), unlo(o1), unhi(o1), unlo(o2), unhi(o2)};
                        float ov[6];
#pragma unroll
                        for (int t = 0; t < 6; ++t) {
                            float en = acc[t][r] + dh[t] + eh[t];
                            float sg = frcp(1.f + __expf(-en));
                            nacc[t] += bh[t] * sg;
                            dacc[t] += sg;
                            ov[t] = od[t] + fmaxf(en, 0.f);
                        }
                        *(u32*)ep       = pk2(ov[0], ov[1]);
                        *(u32*)(ep + 2) = pk2(ov[2], ov[3]);
                        *(u32*)(ep + 4) = pk2(ov[4], ov[5]);
                    }
                }
            }
        }
        // reduce over quads (butterfly across lane bits 4-5)
#pragma unroll
        for (int t = 0; t < 6; ++t) {
            float x = nacc[t], y = dacc[t];
            x += __shfl_xor(x, 16); y += __shfl_xor(y, 16);
            x += __shfl_xor(x, 32); y += __shfl_xor(y, 32);
            nacc[t] = x; dacc[t] = y;
        }
        if (quad == 0) {
            const float* ap = Ah + (long)n * DD + lm * 6;
            float* hp = hbuf + (long)n * DD + lm * 6;
            float val[6];
#pragma unroll
            for (int t = 0; t < 6; ++t)
                val[t] = fmaxf(ap[t] + nacc[t] * frcp(dacc[t] + EPSF), 0.f);
            float2 h0 = *(float2*)hp, h1 = *(float2*)(hp + 2), h2 = *(float2*)(hp + 4);
            *(float2*)(hp)     = make_float2(h0.x + val[0], h0.y + val[1]);
            *(float2*)(hp + 2) = make_float2(h1.x + val[2], h1.y + val[3]);
            *(float2*)(hp + 4) = make_float2(h2.x + val[4], h2.y + val[5]);
        }
        n = n2;
    }
}

// small MLP stage, one thread per output element
__global__ void k_mlp(const float* __restrict__ X, const float* __restrict__ W,
                      const float* __restrict__ B, float* __restrict__ Y,
                      int K, int Dout, int act, long total) {
    long idx = (long)blockIdx.x * blockDim.x + threadIdx.x;
    if (idx >= total) return;
    int row = (int)(idx / Dout);
    int j = (int)(idx - (long)row * Dout);
    const float* xr = X + (long)row * K;
    float acc = B[j];
    for (int k = 0; k < K; ++k) acc = fmaf(xr[k], W[k * Dout + j], acc);
    if (act == 1) acc = fmaxf(acc, 0.f);
    else if (act == 2) acc = frcp(1.f + __expf(-acc));
    Y[idx] = acc;
}

extern "C" void kernel_launch(void* const* d_in, const int* in_sizes, int n_in,
                              void* d_out, int out_size, void* d_ws, size_t ws_size,
                              hipStream_t stream) {
    const float* h_in = (const float*)d_in[0];
    const float* e_in = (const float*)d_in[1];
    const int* src = (const int*)d_in[2];
    const int* dst = (const int*)d_in[3];
    const float* fp_w = (const float*)d_in[4];
    const float* fp_b = (const float*)d_in[5];
    const float* ep_w = (const float*)d_in[6];
    const float* ep_b = (const float*)d_in[7];
    const float* A_w = (const float*)d_in[8];
    const float* A_b = (const float*)d_in[9];
    const float* B_w = (const float*)d_in[10];
    const float* B_b = (const float*)d_in[11];
    const float* C_w = (const float*)d_in[12];
    const float* C_b = (const float*)d_in[13];
    const float* D_w = (const float*)d_in[14];
    const float* D_b = (const float*)d_in[15];
    const float* E_w = (const float*)d_in[16];
    const float* E_b = (const float*)d_in[17];
    const float* mlp0_w = (const float*)d_in[18];
    const float* mlp0_b = (const float*)d_in[19];
    const float* mlp1_w = (const float*)d_in[20];
    const float* mlp1_b = (const float*)d_in[21];
    const float* mlp2_w = (const float*)d_in[22];
    const float* mlp2_b = (const float*)d_in[23];
    float* out = (float*)d_out;

    const size_t ND_ = (size_t)NN * DD;
    const size_t ED_ = (size_t)NE * DD;
    const size_t FRAG = (size_t)NL * 6 * 3 * 64 * 8;   // u16 count per packed tensor
    char* w = (char*)d_ws;
    float* hbuf = (float*)w; w += ND_ * 4;
    float* Ahb  = (float*)w; w += ND_ * 4;
    u16* Bhb = (u16*)w; w += ND_ * 2;
    u16* Dhb = (u16*)w; w += ND_ * 2;
    u16* Ehb = (u16*)w; w += ND_ * 2;
    u16* ebuf = (u16*)w; w += ED_ * 2;
    int* counts  = (int*)w; w += (size_t)NN * 4;
    int* cursor  = (int*)w; w += (size_t)NN * 4;
    int* row_ptr = (int*)w; w += (size_t)(NN + 1) * 4 + 12;
    int* bsum    = (int*)w; w += 256;
    int* eperm   = (int*)w; w += (size_t)NE * 4;
    int* srcp    = (int*)w; w += (size_t)NE * 4;
    u16* awf = (u16*)w; w += FRAG * 2;
    u16* bwf = (u16*)w; w += FRAG * 2;
    u16* cwf = (u16*)w; w += FRAG * 2;
    u16* dwf = (u16*)w; w += FRAG * 2;
    u16* ewf = (u16*)w; w += FRAG * 2;
    u16* wfp = (u16*)w; w += (size_t)6 * 64 * 8 * 2;
    u16* wep = (u16*)w; w += (size_t)6 * 64 * 8 * 2;
    float* w0p = (float*)w; w += (size_t)DD * 48 * 4;
    size_t need = (size_t)(w - (char*)d_ws);
    if (ws_size < need) return;  // uniform -> graph-safe; fails absmax as diagnostic

    // CSR build (dst-sorted edge permutation), multi-block scan
    k_zero4<<<(NN / 4 + 255) / 256, 256, 0, stream>>>(counts, NN / 4);
    k_hist<<<(NE + 255) / 256, 256, 0, stream>>>(dst, counts);
    const int nsb = (NN + 1023) / 1024;
    k_scan1<<<nsb, 1024, 0, stream>>>(counts, row_ptr, bsum, NN);
    k_scan2<<<1, 64, 0, stream>>>(bsum, nsb);
    k_scan3<<<(NN + 255) / 256, 256, 0, stream>>>(row_ptr, cursor, bsum, NN);
    k_scatter<<<(NE + 255) / 256, 256, 0, stream>>>(src, dst, cursor, eperm, srcp);

    // fused weight packing (all layer weights k-permuted; projections canonical)
    const int packTot = 5 * (NL * 6 * 3 * 64) + 768 + DD * 48;
    k_packAll<<<(packTot + 255) / 256, 256, 0, stream>>>(A_w, B_w, C_w, D_w, E_w,
                                                         fp_w, ep_w, mlp0_w,
                                                         awf, bwf, cwf, dwf, ewf,
                                                         wfp, wep, w0p);

    // input projections (h f32 permuted; e bf16 permuted, dst-sorted)
    k_proj_m<false, false, true><<<256, 256, 0, stream>>>(h_in, wfp, fp_b, hbuf, nullptr, NN / 16);
    k_proj_m<true, true, true><<<2048, 256, 0, stream>>>(e_in, wep, ep_b, ebuf, eperm, NE / 16);

    const size_t LFRAG = (size_t)6 * 3 * 64 * 8;
    for (int l = 0; l < NL; ++l) {
        const float* Ab = A_b + (size_t)l * DD;
        const float* Bb = B_b + (size_t)l * DD;
        const float* Cb = C_b + (size_t)l * DD;
        const float* Db = D_b + (size_t)l * DD;
        const float* Eb = E_b + (size_t)l * DD;

        k_gemm4m<<<1280, 256, 0, stream>>>(hbuf,
                                           awf + l * LFRAG, Ab, bwf + l * LFRAG, Bb,
                                           dwf + l * LFRAG, Db, ewf + l * LFRAG, Eb,
                                           Ahb, Bhb, Dhb, Ehb, NN / 16);
        k_node_edge_w<<<2560, 256, 0, stream>>>(ebuf, cwf + l * LFRAG, Cb, Dhb, Ehb, Bhb,
                                                srcp, row_ptr, Ahb, hbuf);
    }

    // MLP readout: 96 -> 48 (relu) -> 24 (relu) -> 10 (sigmoid). Reuse Ahb as temps.
    // Stage 0 uses the permuted-row weight copy (hbuf is in permuted basis).
    float* y1 = Ahb;
    float* y2 = Ahb + (size_t)NN * 48;
    long t0 = (long)NN * 48, t1 = (long)NN * 24, t2 = (long)NN * NCLS;
    k_mlp<<<(int)((t0 + 255) / 256), 256, 0, stream>>>(hbuf, w0p, mlp0_b, y1, DD, 48, 1, t0);
    k_mlp<<<(int)((t1 + 255) / 256), 256, 0, stream>>>(y1, mlp1_w, mlp1_b, y2, 48, 24, 1, t1);
    k_mlp<<<(int)((t2 + 255) / 256), 256, 0, stream>>>(y2, mlp2_w, mlp2_b, out, 24, NCLS, 2, t2);
}

// Round 4
// 1810.614 us; speedup vs baseline: 1.4141x; 1.4141x over previous
//
#include <hip/hip_runtime.h>

#define NN 50000
#define NE 800000
#define DIN 32
#define DD 96
#define NL 4
#define NCLS 10
#define EPSF 1e-6f

typedef unsigned short u16;
typedef unsigned int u32;

typedef __bf16 bf16x8 __attribute__((ext_vector_type(8)));
typedef float f32x4 __attribute__((ext_vector_type(4)));

static __device__ __forceinline__ u16 f2bf(float f) {
    u32 x = __float_as_uint(f);
    x += 0x7FFFu + ((x >> 16) & 1u);   // round-to-nearest-even
    return (u16)(x >> 16);
}
// packed RNE f32x2 -> bf16x2 in one instruction (gfx950)
static __device__ __forceinline__ u32 pk2(float a, float b) {
    u32 r;
    asm("v_cvt_pk_bf16_f32 %0, %1, %2" : "=v"(r) : "v"(a), "v"(b));
    return r;
}
static __device__ __forceinline__ float unlo(u32 u) { return __uint_as_float(u << 16); }
static __device__ __forceinline__ float unhi(u32 u) { return __uint_as_float(u & 0xFFFF0000u); }
static __device__ __forceinline__ float frcp(float x) { return __builtin_amdgcn_rcpf(x); }

__global__ void k_zero4(int* __restrict__ p, long n4) {
    long i = (long)blockIdx.x * blockDim.x + threadIdx.x;
    if (i < n4) ((int4*)p)[i] = make_int4(0, 0, 0, 0);
}

__global__ void k_hist(const int* __restrict__ dst, int* __restrict__ counts) {
    int i = blockIdx.x * blockDim.x + threadIdx.x;
    if (i < NE) atomicAdd(&counts[dst[i]], 1);
}

// multi-block scan, pass 1: per-block local exclusive scan + block sums
__global__ __launch_bounds__(1024) void k_scan1(const int* __restrict__ counts,
                                                int* __restrict__ excl,
                                                int* __restrict__ bsum, int n) {
    __shared__ int wsum[16];
    const int tid = threadIdx.x, lane = tid & 63, wid = tid >> 6;
    const int i = blockIdx.x * 1024 + tid;
    int v = (i < n) ? counts[i] : 0;
    int x = v;
#pragma unroll
    for (int off = 1; off < 64; off <<= 1) {
        int t = __shfl_up(x, (unsigned)off, 64);
        if (lane >= off) x += t;
    }
    if (lane == 63) wsum[wid] = x;
    __syncthreads();
    if (tid < 16) {
        int s = wsum[tid];
#pragma unroll
        for (int off = 1; off < 16; off <<= 1) {
            int t = __shfl_up(s, (unsigned)off, 16);
            if (tid >= off) s += t;
        }
        wsum[tid] = s;
    }
    __syncthreads();
    const int wbase = wid ? wsum[wid - 1] : 0;
    if (i < n) excl[i] = wbase + x - v;
    if (tid == 1023) bsum[blockIdx.x] = wbase + x;
}

// pass 2: exclusive scan of block sums (<=64 blocks), single wave
__global__ void k_scan2(int* __restrict__ bsum, int nb) {
    const int lane = threadIdx.x;
    int v = (lane < nb) ? bsum[lane] : 0;
    int x = v;
#pragma unroll
    for (int off = 1; off < 64; off <<= 1) {
        int t = __shfl_up(x, (unsigned)off, 64);
        if (lane >= off) x += t;
    }
    if (lane < nb) bsum[lane] = x - v;
}

// pass 3: add block offsets -> final row_ptr and cursor copy; row_ptr[n]=NE.
__global__ void k_scan3(int* __restrict__ row_ptr, int* __restrict__ cursor,
                        const int* __restrict__ bsum, int n) {
    int i = blockIdx.x * blockDim.x + threadIdx.x;
    if (i < n) {
        int v = row_ptr[i] + bsum[i >> 10];
        row_ptr[i] = v;
        cursor[i] = v;
    }
    if (i == 0) row_ptr[n] = NE;
}

__global__ void k_scatter(const int* __restrict__ src, const int* __restrict__ dst,
                          int* __restrict__ cursor, int* __restrict__ eperm,
                          int* __restrict__ srcp) {
    int i = blockIdx.x * blockDim.x + threadIdx.x;
    if (i >= NE) return;
    int pos = atomicAdd(&cursor[dst[i]], 1);
    eperm[pos] = i;
    srcp[pos] = src[i];
}

// Fused packer: 5x [NL][96][96] layer weights (all k-permuted: both h-state and
// e-state live in the permuted basis), 2x [32,96] projections (canonical k),
// and the permuted-row copy of mlp0_w.
__global__ void k_packAll(const float* __restrict__ A_w, const float* __restrict__ B_w,
                          const float* __restrict__ C_w, const float* __restrict__ D_w,
                          const float* __restrict__ E_w,
                          const float* __restrict__ fp_w, const float* __restrict__ ep_w,
                          const float* __restrict__ m0w,
                          u16* __restrict__ awf, u16* __restrict__ bwf, u16* __restrict__ cwf,
                          u16* __restrict__ dwf, u16* __restrict__ ewf,
                          u16* __restrict__ wfp, u16* __restrict__ wep,
                          float* __restrict__ w0p) {
    const int PER = NL * 6 * 3 * 64;   // 4608 fragments per tensor
    int q = blockIdx.x * blockDim.x + threadIdx.x;
    if (q < 5 * PER) {
        int which = q / PER;
        int qq = q - which * PER;
        const float* W_all = which == 0 ? A_w : which == 1 ? B_w : which == 2 ? C_w
                           : which == 3 ? D_w : E_w;
        u16* wf = which == 0 ? awf : which == 1 ? bwf : which == 2 ? cwf
                : which == 3 ? dwf : ewf;
        int l = qq / (6 * 3 * 64);
        int rem = qq - l * (6 * 3 * 64);
        int tile = rem / (3 * 64);
        int rem2 = rem - tile * (3 * 64);
        int c = rem2 >> 6, ln = rem2 & 63;
        const float* W = W_all + (long)l * DD * DD;
        int n = tile * 16 + (ln & 15);
        int k0 = c * 32 + (ln >> 4) * 8;
        u16 wv[8];
#pragma unroll
        for (int j = 0; j < 8; ++j) {
            int kk = k0 + j;
            int kact = (kk % 6) * 16 + kk / 6;   // stored-p -> actual feature
            wv[j] = f2bf(W[kact * DD + n]);
        }
        *(uint4*)&wf[(long)qq * 8] = *(uint4*)wv;
    } else if (q < 5 * PER + 768) {
        int qq = q - 5 * PER;
        int which = qq / 384; qq -= which * 384;
        const float* W = which ? ep_w : fp_w;
        u16* wf = which ? wep : wfp;
        int ln = qq & 63;
        int n = (qq >> 6) * 16 + (ln & 15);
        int k0 = (ln >> 4) * 8;
        u16 wv[8];
#pragma unroll
        for (int j = 0; j < 8; ++j) wv[j] = f2bf(W[(k0 + j) * DD + n]);
        *(uint4*)&wf[qq * 8] = *(uint4*)wv;
    } else {
        int qq = q - 5 * PER - 768;
        if (qq < DD * 48) {
            int p = qq / 48, j = qq - p * 48;
            int jp = (p % 6) * 16 + p / 6;       // actual feature of stored p
            w0p[qq] = m0w[jp * 48 + j];
        }
    }
}

// Barrier-free MFMA input projection: one wave per 16-row tile, grid-stride.
// POUT: permuted-basis output (stored p = lm*6+t holds actual col t*16+lm).
// BFOUT selects bf16 (3x u32) vs f32 (3x float2) stores on the POUT path.
template <bool BFOUT, bool PERM, bool POUT>
__global__ __launch_bounds__(256) void k_proj_m(const float* __restrict__ X,
                                                const u16* __restrict__ wf,
                                                const float* __restrict__ B,
                                                void* __restrict__ Y,
                                                const int* __restrict__ eperm,
                                                int ntiles) {
    const int lane = threadIdx.x & 63;
    const int gw = (blockIdx.x * blockDim.x + threadIdx.x) >> 6;
    const int nw = (gridDim.x * blockDim.x) >> 6;
    const int lm = lane & 15, quad = lane >> 4;

    bf16x8 bfr[6];
    float bias[6];
#pragma unroll
    for (int t = 0; t < 6; ++t) {
        bfr[t] = *(const bf16x8*)&wf[(t * 64 + lane) * 8];
        bias[t] = B[t * 16 + lm];
    }

    for (int tile = gw; tile < ntiles; tile += nw) {
        const int row = tile * 16 + lm;
        const long srow = PERM ? (long)eperm[row] : (long)row;
        float4 x0 = *(const float4*)&X[srow * DIN + quad * 8];
        float4 x1 = *(const float4*)&X[srow * DIN + quad * 8 + 4];
        u32 ap[4] = {pk2(x0.x, x0.y), pk2(x0.z, x0.w), pk2(x1.x, x1.y), pk2(x1.z, x1.w)};
        bf16x8 af = *(bf16x8*)ap;
        f32x4 acc[6];
#pragma unroll
        for (int t = 0; t < 6; ++t) {
            acc[t] = (f32x4){bias[t], bias[t], bias[t], bias[t]};
            acc[t] = __builtin_amdgcn_mfma_f32_16x16x32_bf16(af, bfr[t], acc[t], 0, 0, 0);
        }
        const long rbase = (long)tile * 16 + quad * 4;
        if (POUT) {
#pragma unroll
            for (int r = 0; r < 4; ++r) {
                if (BFOUT) {
                    u16* p = (u16*)Y + (rbase + r) * DD + lm * 6;
                    *(u32*)p       = pk2(acc[0][r], acc[1][r]);
                    *(u32*)(p + 2) = pk2(acc[2][r], acc[3][r]);
                    *(u32*)(p + 4) = pk2(acc[4][r], acc[5][r]);
                } else {
                    float* p = (float*)Y + (rbase + r) * DD + lm * 6;
                    *(float2*)(p)     = make_float2(acc[0][r], acc[1][r]);
                    *(float2*)(p + 2) = make_float2(acc[2][r], acc[3][r]);
                    *(float2*)(p + 4) = make_float2(acc[4][r], acc[5][r]);
                }
            }
        } else {
#pragma unroll
            for (int t = 0; t < 6; ++t) {
                const int j = t * 16 + lm;
#pragma unroll
                for (int r = 0; r < 4; ++r) {
                    float v = acc[t][r];
                    if (BFOUT) ((u16*)Y)[(rbase + r) * DD + j] = f2bf(v);
                    else       ((float*)Y)[(rbase + r) * DD + j] = v;
                }
            }
        }
    }
}

// Barrier-free MFMA 4-way node GEMM: wave w of each block handles matrix w.
// All outputs in permuted basis: A -> f32 (3x float2), B/D/E -> bf16 (3x u32).
__global__ __launch_bounds__(256) void k_gemm4m(const float* __restrict__ X,
                                                const u16* __restrict__ awf, const float* __restrict__ ab,
                                                const u16* __restrict__ bwf, const float* __restrict__ bb,
                                                const u16* __restrict__ dwf, const float* __restrict__ db,
                                                const u16* __restrict__ ewf, const float* __restrict__ eb,
                                                float* __restrict__ Y0, u16* __restrict__ Y1,
                                                u16* __restrict__ Y2, u16* __restrict__ Y3,
                                                int ntiles) {
    const int lane = threadIdx.x & 63;
    const int w = threadIdx.x >> 6;   // matrix 0..3
    const int lm = lane & 15, quad = lane >> 4;
    const u16* wf = (w == 0) ? awf : (w == 1) ? bwf : (w == 2) ? dwf : ewf;
    const float* bp = (w == 0) ? ab : (w == 1) ? bb : (w == 2) ? db : eb;

    bf16x8 bfr[6][3];
    float bias[6];
#pragma unroll
    for (int t = 0; t < 6; ++t) {
#pragma unroll
        for (int c = 0; c < 3; ++c)
            bfr[t][c] = *(const bf16x8*)&wf[((t * 3 + c) * 64 + lane) * 8];
        bias[t] = bp[t * 16 + lm];
    }

    for (int tile = blockIdx.x; tile < ntiles; tile += gridDim.x) {
        const float* xr = X + (long)(tile * 16 + lm) * DD;
        bf16x8 a[3];
#pragma unroll
        for (int c = 0; c < 3; ++c) {
            float4 x0 = *(const float4*)&xr[c * 32 + quad * 8];
            float4 x1 = *(const float4*)&xr[c * 32 + quad * 8 + 4];
            u32 ap[4] = {pk2(x0.x, x0.y), pk2(x0.z, x0.w), pk2(x1.x, x1.y), pk2(x1.z, x1.w)};
            a[c] = *(bf16x8*)ap;
        }
        f32x4 acc[6];
#pragma unroll
        for (int t = 0; t < 6; ++t) {
            acc[t] = (f32x4){bias[t], bias[t], bias[t], bias[t]};
#pragma unroll
            for (int c = 0; c < 3; ++c)
                acc[t] = __builtin_amdgcn_mfma_f32_16x16x32_bf16(a[c], bfr[t][c], acc[t], 0, 0, 0);
        }
        const long rbase = (long)tile * 16 + quad * 4;
        if (w == 0) {
#pragma unroll
            for (int r = 0; r < 4; ++r) {
                float* p = Y0 + (rbase + r) * DD + lm * 6;
                *(float2*)(p)     = make_float2(acc[0][r], acc[1][r]);
                *(float2*)(p + 2) = make_float2(acc[2][r], acc[3][r]);
                *(float2*)(p + 4) = make_float2(acc[4][r], acc[5][r]);
            }
        } else {
            u16* Yp = (w == 1) ? Y1 : (w == 2) ? Y2 : Y3;
#pragma unroll
            for (int r = 0; r < 4; ++r) {
                u16* p = Yp + (rbase + r) * DD + lm * 6;
                *(u32*)p       = pk2(acc[0][r], acc[1][r]);
                *(u32*)(p + 2) = pk2(acc[2][r], acc[3][r]);
                *(u32*)(p + 4) = pk2(acc[4][r], acc[5][r]);
            }
        }
    }
}

// issue Dh/Bh gathers for chunk CH into register sets GD/GB (row-predicated)
#define GISSUE(GD, GB, CH)                                                      \
    {                                                                           \
        const int _rows = r1 - (CH);                                            \
        _Pragma("unroll")                                                       \
        for (int r = 0; r < 4; ++r) {                                           \
            const int rl = quad * 4 + r;                                        \
            if (rl < _rows) {                                                   \
                const long s = srcp[(CH) + rl];                                 \
                const u16* dp = Dh + s * DD + lm * 6;                           \
                const u16* bp = Bh + s * DD + lm * 6;                           \
                GD[r * 3 + 0] = *(const u32*)dp;                                \
                GD[r * 3 + 1] = *(const u32*)(dp + 2);                          \
                GD[r * 3 + 2] = *(const u32*)(dp + 4);                          \
                GB[r * 3 + 0] = *(const u32*)bp;                                \
                GB[r * 3 + 1] = *(const u32*)(bp + 2);                          \
                GB[r * 3 + 2] = *(const u32*)(bp + 4);                          \
            }                                                                   \
        }                                                                       \
    }

// one 16-edge chunk: MFMA -> prefetch next a + next gathers -> epilogue (uses
// current gather set GDC/GBC from registers; ebuf old-value loads stay late)
#define NBODY(GDC, GBC, GDN, GBN)                                               \
    {                                                                           \
        const int rows = r1 - chunk < 16 ? r1 - chunk : 16;                     \
        f32x4 acc[6];                                                           \
        _Pragma("unroll")                                                       \
        for (int t = 0; t < 6; ++t) {                                           \
            acc[t] = (f32x4){cb[t], cb[t], cb[t], cb[t]};                       \
            _Pragma("unroll")                                                   \
            for (int c = 0; c < 3; ++c)                                         \
                acc[t] = __builtin_amdgcn_mfma_f32_16x16x32_bf16(a[c], bfrag[t][c], acc[t], 0, 0, 0); \
        }                                                                       \
        const int nchunk = chunk + 16;                                          \
        if (nchunk < r1) {                                                      \
            const int rows2 = r1 - nchunk < 16 ? r1 - nchunk : 16;              \
            const long arow2 = nchunk + (lm < rows2 ? lm : 0);                  \
            _Pragma("unroll")                                                   \
            for (int c = 0; c < 3; ++c)                                         \
                a[c] = *(const bf16x8*)&ebuf[arow2 * DD + c * 32 + quad * 8];   \
            GISSUE(GDN, GBN, nchunk);                                           \
        }                                                                       \
        _Pragma("unroll")                                                       \
        for (int r = 0; r < 4; ++r) {                                           \
            const int rl = quad * 4 + r;                                        \
            if (rl < rows) {                                                    \
                u16* ep = ebuf + (long)(chunk + rl) * DD + lm * 6;              \
                u32 o0 = *(const u32*)ep, o1 = *(const u32*)(ep + 2), o2 = *(const u32*)(ep + 4); \
                float dh[6] = {unlo(GDC[r * 3]), unhi(GDC[r * 3]), unlo(GDC[r * 3 + 1]), \
                               unhi(GDC[r * 3 + 1]), unlo(GDC[r * 3 + 2]), unhi(GDC[r * 3 + 2])}; \
                float bh[6] = {unlo(GBC[r * 3]), unhi(GBC[r * 3]), unlo(GBC[r * 3 + 1]), \
                               unhi(GBC[r * 3 + 1]), unlo(GBC[r * 3 + 2]), unhi(GBC[r * 3 + 2])}; \
                float od[6] = {unlo(o0), unhi(o0), unlo(o1), unhi(o1), unlo(o2), unhi(o2)}; \
                float ov[6];                                                    \
                _Pragma("unroll")                                               \
                for (int t = 0; t < 6; ++t) {                                   \
                    float en = acc[t][r] + dh[t] + eh[t];                       \
                    float sg = frcp(1.f + __expf(-en));                         \
                    nacc[t] += bh[t] * sg;                                      \
                    dacc[t] += sg;                                              \
                    ov[t] = od[t] + fmaxf(en, 0.f);                             \
                }                                                               \
                *(u32*)ep       = pk2(ov[0], ov[1]);                            \
                *(u32*)(ep + 2) = pk2(ov[2], ov[3]);                            \
                *(u32*)(ep + 4) = pk2(ov[4], ov[5]);                            \
            }                                                                   \
        }                                                                       \
    }

// Barrier-free, LDS-free, atomic-free fused edge+aggregate: one wave per node
// (grid-stride). Weight fragments in registers (R2 structure). NEW: Dh/Bh
// gathers software-pipelined one chunk ahead via static ping-pong register
// sets (uniform parity branch: r0/r1 are wave-uniform).
__global__ __launch_bounds__(256) void k_node_edge_w(u16* ebuf,
                                                     const u16* __restrict__ cwf,  // k-permuted pack
                                                     const float* __restrict__ Cb,
                                                     const u16* __restrict__ Dh,
                                                     const u16* __restrict__ Eh,
                                                     const u16* __restrict__ Bh,
                                                     const int* __restrict__ srcp,
                                                     const int* __restrict__ row_ptr,
                                                     const float* __restrict__ Ah,
                                                     float* __restrict__ hbuf) {
    const int lane = threadIdx.x & 63;
    const int gw = (blockIdx.x * blockDim.x + threadIdx.x) >> 6;
    const int nw = (gridDim.x * blockDim.x) >> 6;
    const int lm = lane & 15, quad = lane >> 4;

    bf16x8 bfrag[6][3];
    float cb[6];
#pragma unroll
    for (int t = 0; t < 6; ++t) {
#pragma unroll
        for (int c = 0; c < 3; ++c)
            bfrag[t][c] = *(const bf16x8*)&cwf[((t * 3 + c) * 64 + lane) * 8];
        cb[t] = Cb[t * 16 + lm];   // stored p=lm*6+t <-> actual col t*16+lm
    }

    for (int n = gw; n < NN; n += nw) {
        const int r0 = row_ptr[n], r1 = row_ptr[n + 1];
        float nacc[6] = {0.f, 0.f, 0.f, 0.f, 0.f, 0.f};
        float dacc[6] = {0.f, 0.f, 0.f, 0.f, 0.f, 0.f};

        if (r0 < r1) {
            float eh[6];
            {
                const u16* ep = Eh + (long)n * DD + lm * 6;
                u32 e0 = *(const u32*)ep, e1 = *(const u32*)(ep + 2), e2 = *(const u32*)(ep + 4);
                eh[0] = unlo(e0); eh[1] = unhi(e0); eh[2] = unlo(e1);
                eh[3] = unhi(e1); eh[4] = unlo(e2); eh[5] = unhi(e2);
            }
            // preload first chunk's A-fragments + issue first chunk's gathers
            bf16x8 a[3];
            {
                const int rows = r1 - r0 < 16 ? r1 - r0 : 16;
                const long arow = r0 + (lm < rows ? lm : 0);
#pragma unroll
                for (int c = 0; c < 3; ++c)
                    a[c] = *(const bf16x8*)&ebuf[arow * DD + c * 32 + quad * 8];
            }
            u32 gdA[12], gbA[12], gdB[12], gbB[12];
            GISSUE(gdA, gbA, r0);

            int chunk = r0;
            int par = 0;
            while (chunk < r1) {
                if (par == 0) {
                    NBODY(gdA, gbA, gdB, gbB)
                } else {
                    NBODY(gdB, gbB, gdA, gbA)
                }
                par ^= 1;
                chunk += 16;
            }
        }
        // reduce over quads (butterfly across lane bits 4-5)
#pragma unroll
        for (int t = 0; t < 6; ++t) {
            float x = nacc[t], y = dacc[t];
            x += __shfl_xor(x, 16); y += __shfl_xor(y, 16);
            x += __shfl_xor(x, 32); y += __shfl_xor(y, 32);
            nacc[t] = x; dacc[t] = y;
        }
        if (quad == 0) {
            const float* ap = Ah + (long)n * DD + lm * 6;
            float* hp = hbuf + (long)n * DD + lm * 6;
            float val[6];
#pragma unroll
            for (int t = 0; t < 6; ++t)
                val[t] = fmaxf(ap[t] + nacc[t] * frcp(dacc[t] + EPSF), 0.f);
            float2 h0 = *(float2*)hp, h1 = *(float2*)(hp + 2), h2 = *(float2*)(hp + 4);
            *(float2*)(hp)     = make_float2(h0.x + val[0], h0.y + val[1]);
            *(float2*)(hp + 2) = make_float2(h1.x + val[2], h1.y + val[3]);
            *(float2*)(hp + 4) = make_float2(h2.x + val[4], h2.y + val[5]);
        }
    }
}

// small MLP stage, one thread per output element
__global__ void k_mlp(const float* __restrict__ X, const float* __restrict__ W,
                      const float* __restrict__ B, float* __restrict__ Y,
                      int K, int Dout, int act, long total) {
    long idx = (long)blockIdx.x * blockDim.x + threadIdx.x;
    if (idx >= total) return;
    int row = (int)(idx / Dout);
    int j = (int)(idx - (long)row * Dout);
    const float* xr = X + (long)row * K;
    float acc = B[j];
    for (int k = 0; k < K; ++k) acc = fmaf(xr[k], W[k * Dout + j], acc);
    if (act == 1) acc = fmaxf(acc, 0.f);
    else if (act == 2) acc = frcp(1.f + __expf(-acc));
    Y[idx] = acc;
}

extern "C" void kernel_launch(void* const* d_in, const int* in_sizes, int n_in,
                              void* d_out, int out_size, void* d_ws, size_t ws_size,
                              hipStream_t stream) {
    const float* h_in = (const float*)d_in[0];
    const float* e_in = (const float*)d_in[1];
    const int* src = (const int*)d_in[2];
    const int* dst = (const int*)d_in[3];
    const float* fp_w = (const float*)d_in[4];
    const float* fp_b = (const float*)d_in[5];
    const float* ep_w = (const float*)d_in[6];
    const float* ep_b = (const float*)d_in[7];
    const float* A_w = (const float*)d_in[8];
    const float* A_b = (const float*)d_in[9];
    const float* B_w = (const float*)d_in[10];
    const float* B_b = (const float*)d_in[11];
    const float* C_w = (const float*)d_in[12];
    const float* C_b = (const float*)d_in[13];
    const float* D_w = (const float*)d_in[14];
    const float* D_b = (const float*)d_in[15];
    const float* E_w = (const float*)d_in[16];
    const float* E_b = (const float*)d_in[17];
    const float* mlp0_w = (const float*)d_in[18];
    const float* mlp0_b = (const float*)d_in[19];
    const float* mlp1_w = (const float*)d_in[20];
    const float* mlp1_b = (const float*)d_in[21];
    const float* mlp2_w = (const float*)d_in[22];
    const float* mlp2_b = (const float*)d_in[23];
    float* out = (float*)d_out;

    const size_t ND_ = (size_t)NN * DD;
    const size_t ED_ = (size_t)NE * DD;
    const size_t FRAG = (size_t)NL * 6 * 3 * 64 * 8;   // u16 count per packed tensor
    char* w = (char*)d_ws;
    float* hbuf = (float*)w; w += ND_ * 4;
    float* Ahb  = (float*)w; w += ND_ * 4;
    u16* Bhb = (u16*)w; w += ND_ * 2;
    u16* Dhb = (u16*)w; w += ND_ * 2;
    u16* Ehb = (u16*)w; w += ND_ * 2;
    u16* ebuf = (u16*)w; w += ED_ * 2;
    int* counts  = (int*)w; w += (size_t)NN * 4;
    int* cursor  = (int*)w; w += (size_t)NN * 4;
    int* row_ptr = (int*)w; w += (size_t)(NN + 1) * 4 + 12;
    int* bsum    = (int*)w; w += 256;
    int* eperm   = (int*)w; w += (size_t)NE * 4;
    int* srcp    = (int*)w; w += (size_t)NE * 4;
    u16* awf = (u16*)w; w += FRAG * 2;
    u16* bwf = (u16*)w; w += FRAG * 2;
    u16* cwf = (u16*)w; w += FRAG * 2;
    u16* dwf = (u16*)w; w += FRAG * 2;
    u16* ewf = (u16*)w; w += FRAG * 2;
    u16* wfp = (u16*)w; w += (size_t)6 * 64 * 8 * 2;
    u16* wep = (u16*)w; w += (size_t)6 * 64 * 8 * 2;
    float* w0p = (float*)w; w += (size_t)DD * 48 * 4;
    size_t need = (size_t)(w - (char*)d_ws);
    if (ws_size < need) return;  // uniform -> graph-safe; fails absmax as diagnostic

    // CSR build (dst-sorted edge permutation), multi-block scan
    k_zero4<<<(NN / 4 + 255) / 256, 256, 0, stream>>>(counts, NN / 4);
    k_hist<<<(NE + 255) / 256, 256, 0, stream>>>(dst, counts);
    const int nsb = (NN + 1023) / 1024;
    k_scan1<<<nsb, 1024, 0, stream>>>(counts, row_ptr, bsum, NN);
    k_scan2<<<1, 64, 0, stream>>>(bsum, nsb);
    k_scan3<<<(NN + 255) / 256, 256, 0, stream>>>(row_ptr, cursor, bsum, NN);
    k_scatter<<<(NE + 255) / 256, 256, 0, stream>>>(src, dst, cursor, eperm, srcp);

    // fused weight packing (all layer weights k-permuted; projections canonical)
    const int packTot = 5 * (NL * 6 * 3 * 64) + 768 + DD * 48;
    k_packAll<<<(packTot + 255) / 256, 256, 0, stream>>>(A_w, B_w, C_w, D_w, E_w,
                                                         fp_w, ep_w, mlp0_w,
                                                         awf, bwf, cwf, dwf, ewf,
                                                         wfp, wep, w0p);

    // input projections (h f32 permuted; e bf16 permuted, dst-sorted)
    k_proj_m<false, false, true><<<256, 256, 0, stream>>>(h_in, wfp, fp_b, hbuf, nullptr, NN / 16);
    k_proj_m<true, true, true><<<2048, 256, 0, stream>>>(e_in, wep, ep_b, ebuf, eperm, NE / 16);

    const size_t LFRAG = (size_t)6 * 3 * 64 * 8;
    for (int l = 0; l < NL; ++l) {
        const float* Ab = A_b + (size_t)l * DD;
        const float* Bb = B_b + (size_t)l * DD;
        const float* Cb = C_b + (size_t)l * DD;
        const float* Db = D_b + (size_t)l * DD;
        const float* Eb = E_b + (size_t)l * DD;

        k_gemm4m<<<1280, 256, 0, stream>>>(hbuf,
                                           awf + l * LFRAG, Ab, bwf + l * LFRAG, Bb,
                                           dwf + l * LFRAG, Db, ewf + l * LFRAG, Eb,
                                           Ahb, Bhb, Dhb, Ehb, NN / 16);
        k_node_edge_w<<<2560, 256, 0, stream>>>(ebuf, cwf + l * LFRAG, Cb, Dhb, Ehb, Bhb,
                                                srcp, row_ptr, Ahb, hbuf);
    }

    // MLP readout: 96 -> 48 (relu) -> 24 (relu) -> 10 (sigmoid). Reuse Ahb as temps.
    // Stage 0 uses the permuted-row weight copy (hbuf is in permuted basis).
    float* y1 = Ahb;
    float* y2 = Ahb + (size_t)NN * 48;
    long t0 = (long)NN * 48, t1 = (long)NN * 24, t2 = (long)NN * NCLS;
    k_mlp<<<(int)((t0 + 255) / 256), 256, 0, stream>>>(hbuf, w0p, mlp0_b, y1, DD, 48, 1, t0);
    k_mlp<<<(int)((t1 + 255) / 256), 256, 0, stream>>>(y1, mlp1_w, mlp1_b, y2, 48, 24, 1, t1);
    k_mlp<<<(int)((t2 + 255) / 256), 256, 0, stream>>>(y2, mlp2_w, mlp2_b, out, 24, NCLS, 2, t2);
}

// Round 5
// 1761.218 us; speedup vs baseline: 1.4538x; 1.0280x over previous
//
#include <hip/hip_runtime.h>

#define NN 50000
#define NE 800000
#define DIN 32
#define DD 96
#define NL 4
#define NCLS 10
#define EPSF 1e-6f

typedef unsigned short u16;
typedef unsigned int u32;

typedef __bf16 bf16x8 __attribute__((ext_vector_type(8)));
typedef float f32x4 __attribute__((ext_vector_type(4)));

static __device__ __forceinline__ u16 f2bf(float f) {
    u32 x = __float_as_uint(f);
    x += 0x7FFFu + ((x >> 16) & 1u);   // round-to-nearest-even
    return (u16)(x >> 16);
}
// packed RNE f32x2 -> bf16x2 in one instruction (gfx950)
static __device__ __forceinline__ u32 pk2(float a, float b) {
    u32 r;
    asm("v_cvt_pk_bf16_f32 %0, %1, %2" : "=v"(r) : "v"(a), "v"(b));
    return r;
}
static __device__ __forceinline__ float unlo(u32 u) { return __uint_as_float(u << 16); }
static __device__ __forceinline__ float unhi(u32 u) { return __uint_as_float(u & 0xFFFF0000u); }
static __device__ __forceinline__ float frcp(float x) { return __builtin_amdgcn_rcpf(x); }

__global__ void k_zero4(int* __restrict__ p, long n4) {
    long i = (long)blockIdx.x * blockDim.x + threadIdx.x;
    if (i < n4) ((int4*)p)[i] = make_int4(0, 0, 0, 0);
}

__global__ void k_hist(const int* __restrict__ dst, int* __restrict__ counts) {
    int i = blockIdx.x * blockDim.x + threadIdx.x;
    if (i < NE) atomicAdd(&counts[dst[i]], 1);
}

// multi-block scan, pass 1: per-block local exclusive scan + block sums
__global__ __launch_bounds__(1024) void k_scan1(const int* __restrict__ counts,
                                                int* __restrict__ excl,
                                                int* __restrict__ bsum, int n) {
    __shared__ int wsum[16];
    const int tid = threadIdx.x, lane = tid & 63, wid = tid >> 6;
    const int i = blockIdx.x * 1024 + tid;
    int v = (i < n) ? counts[i] : 0;
    int x = v;
#pragma unroll
    for (int off = 1; off < 64; off <<= 1) {
        int t = __shfl_up(x, (unsigned)off, 64);
        if (lane >= off) x += t;
    }
    if (lane == 63) wsum[wid] = x;
    __syncthreads();
    if (tid < 16) {
        int s = wsum[tid];
#pragma unroll
        for (int off = 1; off < 16; off <<= 1) {
            int t = __shfl_up(s, (unsigned)off, 16);
            if (tid >= off) s += t;
        }
        wsum[tid] = s;
    }
    __syncthreads();
    const int wbase = wid ? wsum[wid - 1] : 0;
    if (i < n) excl[i] = wbase + x - v;
    if (tid == 1023) bsum[blockIdx.x] = wbase + x;
}

// pass 2: exclusive scan of block sums (<=64 blocks), single wave
__global__ void k_scan2(int* __restrict__ bsum, int nb) {
    const int lane = threadIdx.x;
    int v = (lane < nb) ? bsum[lane] : 0;
    int x = v;
#pragma unroll
    for (int off = 1; off < 64; off <<= 1) {
        int t = __shfl_up(x, (unsigned)off, 64);
        if (lane >= off) x += t;
    }
    if (lane < nb) bsum[lane] = x - v;
}

// pass 3: add block offsets -> final row_ptr and cursor copy; row_ptr[n]=NE.
__global__ void k_scan3(int* __restrict__ row_ptr, int* __restrict__ cursor,
                        const int* __restrict__ bsum, int n) {
    int i = blockIdx.x * blockDim.x + threadIdx.x;
    if (i < n) {
        int v = row_ptr[i] + bsum[i >> 10];
        row_ptr[i] = v;
        cursor[i] = v;
    }
    if (i == 0) row_ptr[n] = NE;
}

__global__ void k_scatter(const int* __restrict__ src, const int* __restrict__ dst,
                          int* __restrict__ cursor, int* __restrict__ eperm,
                          int* __restrict__ srcp) {
    int i = blockIdx.x * blockDim.x + threadIdx.x;
    if (i >= NE) return;
    int pos = atomicAdd(&cursor[dst[i]], 1);
    eperm[pos] = i;
    srcp[pos] = src[i];
}

// Fused packer: 5x [NL][96][96] layer weights (all k-permuted: both h-state and
// e-state live in the permuted basis), 2x [32,96] projections (canonical k),
// and the permuted-row copy of mlp0_w.
__global__ void k_packAll(const float* __restrict__ A_w, const float* __restrict__ B_w,
                          const float* __restrict__ C_w, const float* __restrict__ D_w,
                          const float* __restrict__ E_w,
                          const float* __restrict__ fp_w, const float* __restrict__ ep_w,
                          const float* __restrict__ m0w,
                          u16* __restrict__ awf, u16* __restrict__ bwf, u16* __restrict__ cwf,
                          u16* __restrict__ dwf, u16* __restrict__ ewf,
                          u16* __restrict__ wfp, u16* __restrict__ wep,
                          float* __restrict__ w0p) {
    const int PER = NL * 6 * 3 * 64;   // 4608 fragments per tensor
    int q = blockIdx.x * blockDim.x + threadIdx.x;
    if (q < 5 * PER) {
        int which = q / PER;
        int qq = q - which * PER;
        const float* W_all = which == 0 ? A_w : which == 1 ? B_w : which == 2 ? C_w
                           : which == 3 ? D_w : E_w;
        u16* wf = which == 0 ? awf : which == 1 ? bwf : which == 2 ? cwf
                : which == 3 ? dwf : ewf;
        int l = qq / (6 * 3 * 64);
        int rem = qq - l * (6 * 3 * 64);
        int tile = rem / (3 * 64);
        int rem2 = rem - tile * (3 * 64);
        int c = rem2 >> 6, ln = rem2 & 63;
        const float* W = W_all + (long)l * DD * DD;
        int n = tile * 16 + (ln & 15);
        int k0 = c * 32 + (ln >> 4) * 8;
        u16 wv[8];
#pragma unroll
        for (int j = 0; j < 8; ++j) {
            int kk = k0 + j;
            int kact = (kk % 6) * 16 + kk / 6;   // stored-p -> actual feature
            wv[j] = f2bf(W[kact * DD + n]);
        }
        *(uint4*)&wf[(long)qq * 8] = *(uint4*)wv;
    } else if (q < 5 * PER + 768) {
        int qq = q - 5 * PER;
        int which = qq / 384; qq -= which * 384;
        const float* W = which ? ep_w : fp_w;
        u16* wf = which ? wep : wfp;
        int ln = qq & 63;
        int n = (qq >> 6) * 16 + (ln & 15);
        int k0 = (ln >> 4) * 8;
        u16 wv[8];
#pragma unroll
        for (int j = 0; j < 8; ++j) wv[j] = f2bf(W[(k0 + j) * DD + n]);
        *(uint4*)&wf[qq * 8] = *(uint4*)wv;
    } else {
        int qq = q - 5 * PER - 768;
        if (qq < DD * 48) {
            int p = qq / 48, j = qq - p * 48;
            int jp = (p % 6) * 16 + p / 6;       // actual feature of stored p
            w0p[qq] = m0w[jp * 48 + j];
        }
    }
}

// Barrier-free MFMA input projection: one wave per 16-row tile, grid-stride.
// POUT: permuted-basis output (stored p = lm*6+t holds actual col t*16+lm).
// BFOUT selects bf16 (3x u32) vs f32 (3x float2) stores on the POUT path.
template <bool BFOUT, bool PERM, bool POUT>
__global__ __launch_bounds__(256) void k_proj_m(const float* __restrict__ X,
                                                const u16* __restrict__ wf,
                                                const float* __restrict__ B,
                                                void* __restrict__ Y,
                                                const int* __restrict__ eperm,
                                                int ntiles) {
    const int lane = threadIdx.x & 63;
    const int gw = (blockIdx.x * blockDim.x + threadIdx.x) >> 6;
    const int nw = (gridDim.x * blockDim.x) >> 6;
    const int lm = lane & 15, quad = lane >> 4;

    bf16x8 bfr[6];
    float bias[6];
#pragma unroll
    for (int t = 0; t < 6; ++t) {
        bfr[t] = *(const bf16x8*)&wf[(t * 64 + lane) * 8];
        bias[t] = B[t * 16 + lm];
    }

    for (int tile = gw; tile < ntiles; tile += nw) {
        const int row = tile * 16 + lm;
        const long srow = PERM ? (long)eperm[row] : (long)row;
        float4 x0 = *(const float4*)&X[srow * DIN + quad * 8];
        float4 x1 = *(const float4*)&X[srow * DIN + quad * 8 + 4];
        u32 ap[4] = {pk2(x0.x, x0.y), pk2(x0.z, x0.w), pk2(x1.x, x1.y), pk2(x1.z, x1.w)};
        bf16x8 af = *(bf16x8*)ap;
        f32x4 acc[6];
#pragma unroll
        for (int t = 0; t < 6; ++t) {
            acc[t] = (f32x4){bias[t], bias[t], bias[t], bias[t]};
            acc[t] = __builtin_amdgcn_mfma_f32_16x16x32_bf16(af, bfr[t], acc[t], 0, 0, 0);
        }
        const long rbase = (long)tile * 16 + quad * 4;
        if (POUT) {
#pragma unroll
            for (int r = 0; r < 4; ++r) {
                if (BFOUT) {
                    u16* p = (u16*)Y + (rbase + r) * DD + lm * 6;
                    *(u32*)p       = pk2(acc[0][r], acc[1][r]);
                    *(u32*)(p + 2) = pk2(acc[2][r], acc[3][r]);
                    *(u32*)(p + 4) = pk2(acc[4][r], acc[5][r]);
                } else {
                    float* p = (float*)Y + (rbase + r) * DD + lm * 6;
                    *(float2*)(p)     = make_float2(acc[0][r], acc[1][r]);
                    *(float2*)(p + 2) = make_float2(acc[2][r], acc[3][r]);
                    *(float2*)(p + 4) = make_float2(acc[4][r], acc[5][r]);
                }
            }
        } else {
#pragma unroll
            for (int t = 0; t < 6; ++t) {
                const int j = t * 16 + lm;
#pragma unroll
                for (int r = 0; r < 4; ++r) {
                    float v = acc[t][r];
                    if (BFOUT) ((u16*)Y)[(rbase + r) * DD + j] = f2bf(v);
                    else       ((float*)Y)[(rbase + r) * DD + j] = v;
                }
            }
        }
    }
}

// Barrier-free MFMA 4-way node GEMM: wave w of each block handles matrix w.
// All outputs in permuted basis: A -> f32 (3x float2), B/D/E -> bf16 (3x u32).
__global__ __launch_bounds__(256) void k_gemm4m(const float* __restrict__ X,
                                                const u16* __restrict__ awf, const float* __restrict__ ab,
                                                const u16* __restrict__ bwf, const float* __restrict__ bb,
                                                const u16* __restrict__ dwf, const float* __restrict__ db,
                                                const u16* __restrict__ ewf, const float* __restrict__ eb,
                                                float* __restrict__ Y0, u16* __restrict__ Y1,
                                                u16* __restrict__ Y2, u16* __restrict__ Y3,
                                                int ntiles) {
    const int lane = threadIdx.x & 63;
    const int w = threadIdx.x >> 6;   // matrix 0..3
    const int lm = lane & 15, quad = lane >> 4;
    const u16* wf = (w == 0) ? awf : (w == 1) ? bwf : (w == 2) ? dwf : ewf;
    const float* bp = (w == 0) ? ab : (w == 1) ? bb : (w == 2) ? db : eb;

    bf16x8 bfr[6][3];
    float bias[6];
#pragma unroll
    for (int t = 0; t < 6; ++t) {
#pragma unroll
        for (int c = 0; c < 3; ++c)
            bfr[t][c] = *(const bf16x8*)&wf[((t * 3 + c) * 64 + lane) * 8];
        bias[t] = bp[t * 16 + lm];
    }

    for (int tile = blockIdx.x; tile < ntiles; tile += gridDim.x) {
        const float* xr = X + (long)(tile * 16 + lm) * DD;
        bf16x8 a[3];
#pragma unroll
        for (int c = 0; c < 3; ++c) {
            float4 x0 = *(const float4*)&xr[c * 32 + quad * 8];
            float4 x1 = *(const float4*)&xr[c * 32 + quad * 8 + 4];
            u32 ap[4] = {pk2(x0.x, x0.y), pk2(x0.z, x0.w), pk2(x1.x, x1.y), pk2(x1.z, x1.w)};
            a[c] = *(bf16x8*)ap;
        }
        f32x4 acc[6];
#pragma unroll
        for (int t = 0; t < 6; ++t) {
            acc[t] = (f32x4){bias[t], bias[t], bias[t], bias[t]};
#pragma unroll
            for (int c = 0; c < 3; ++c)
                acc[t] = __builtin_amdgcn_mfma_f32_16x16x32_bf16(a[c], bfr[t][c], acc[t], 0, 0, 0);
        }
        const long rbase = (long)tile * 16 + quad * 4;
        if (w == 0) {
#pragma unroll
            for (int r = 0; r < 4; ++r) {
                float* p = Y0 + (rbase + r) * DD + lm * 6;
                *(float2*)(p)     = make_float2(acc[0][r], acc[1][r]);
                *(float2*)(p + 2) = make_float2(acc[2][r], acc[3][r]);
                *(float2*)(p + 4) = make_float2(acc[4][r], acc[5][r]);
            }
        } else {
            u16* Yp = (w == 1) ? Y1 : (w == 2) ? Y2 : Y3;
#pragma unroll
            for (int r = 0; r < 4; ++r) {
                u16* p = Yp + (rbase + r) * DD + lm * 6;
                *(u32*)p       = pk2(acc[0][r], acc[1][r]);
                *(u32*)(p + 2) = pk2(acc[2][r], acc[3][r]);
                *(u32*)(p + 4) = pk2(acc[4][r], acc[5][r]);
            }
        }
    }
}

// Barrier-free, LDS-free, atomic-free fused edge+aggregate: one wave per node
// (grid-stride). R2 structure + SAME-CHUNK batched gathers: all 24 Dh/Bh
// loads for the current chunk are issued after the MFMA and before any
// epilogue compute (pinned by one sched_barrier), so ~24 loads overlap in
// flight instead of ~6 per r-step. ebuf old-value loads are issued AFTER the
// gathers (in-order vmcnt -> their wait is covered by the gather wait).
// Only next-chunk state carried: srcp values (4 regs) + A-fragments (24 regs,
// as in R2) -- both consumed after a gather-wait, avoiding R4's in-order
// vmcnt poisoning.
__global__ __launch_bounds__(256) void k_node_edge_w(u16* ebuf,
                                                     const u16* __restrict__ cwf,  // k-permuted pack
                                                     const float* __restrict__ Cb,
                                                     const u16* __restrict__ Dh,
                                                     const u16* __restrict__ Eh,
                                                     const u16* __restrict__ Bh,
                                                     const int* __restrict__ srcp,
                                                     const int* __restrict__ row_ptr,
                                                     const float* __restrict__ Ah,
                                                     float* __restrict__ hbuf) {
    const int lane = threadIdx.x & 63;
    const int gw = (blockIdx.x * blockDim.x + threadIdx.x) >> 6;
    const int nw = (gridDim.x * blockDim.x) >> 6;
    const int lm = lane & 15, quad = lane >> 4;

    bf16x8 bfrag[6][3];
    float cb[6];
#pragma unroll
    for (int t = 0; t < 6; ++t) {
#pragma unroll
        for (int c = 0; c < 3; ++c)
            bfrag[t][c] = *(const bf16x8*)&cwf[((t * 3 + c) * 64 + lane) * 8];
        cb[t] = Cb[t * 16 + lm];   // stored p=lm*6+t <-> actual col t*16+lm
    }

    for (int n = gw; n < NN; n += nw) {
        const int r0 = row_ptr[n], r1 = row_ptr[n + 1];
        float nacc[6] = {0.f, 0.f, 0.f, 0.f, 0.f, 0.f};
        float dacc[6] = {0.f, 0.f, 0.f, 0.f, 0.f, 0.f};

        if (r0 < r1) {
            float eh[6];
            {
                const u16* ep = Eh + (long)n * DD + lm * 6;
                u32 e0 = *(const u32*)ep, e1 = *(const u32*)(ep + 2), e2 = *(const u32*)(ep + 4);
                eh[0] = unlo(e0); eh[1] = unhi(e0); eh[2] = unlo(e1);
                eh[3] = unhi(e1); eh[4] = unlo(e2); eh[5] = unhi(e2);
            }
            // preload first chunk's A-fragments + srcp
            bf16x8 a[3];
            {
                const int rows = r1 - r0 < 16 ? r1 - r0 : 16;
                const long arow = r0 + (lm < rows ? lm : 0);
#pragma unroll
                for (int c = 0; c < 3; ++c)
                    a[c] = *(const bf16x8*)&ebuf[arow * DD + c * 32 + quad * 8];
            }
            int sr[4];
#pragma unroll
            for (int r = 0; r < 4; ++r) {
                const int rl = quad * 4 + r;
                sr[r] = (r0 + rl < r1) ? srcp[r0 + rl] : 0;
            }

            for (int chunk = r0; chunk < r1; chunk += 16) {
                const int rows = r1 - chunk < 16 ? r1 - chunk : 16;
                f32x4 acc[6];
#pragma unroll
                for (int t = 0; t < 6; ++t) {
                    acc[t] = (f32x4){cb[t], cb[t], cb[t], cb[t]};
#pragma unroll
                    for (int c = 0; c < 3; ++c)
                        acc[t] = __builtin_amdgcn_mfma_f32_16x16x32_bf16(a[c], bfrag[t][c], acc[t], 0, 0, 0);
                }
                // prefetch next chunk's A-fragments + srcp (consumed next iter,
                // after this chunk's gather-wait -> latency fully hidden)
                const int nchunk = chunk + 16;
                int srn[4] = {0, 0, 0, 0};
                if (nchunk < r1) {
                    const int rows2 = r1 - nchunk < 16 ? r1 - nchunk : 16;
                    const long arow2 = nchunk + (lm < rows2 ? lm : 0);
#pragma unroll
                    for (int c = 0; c < 3; ++c)
                        a[c] = *(const bf16x8*)&ebuf[arow2 * DD + c * 32 + quad * 8];
#pragma unroll
                    for (int r = 0; r < 4; ++r) {
                        const int rl = quad * 4 + r;
                        if (nchunk + rl < r1) srn[r] = srcp[nchunk + rl];
                    }
                }
                // batched gathers for the CURRENT chunk: 24 independent loads
                u32 gd[12], gb[12];
#pragma unroll
                for (int r = 0; r < 4; ++r) {
                    const int rl = quad * 4 + r;
                    if (rl < rows) {
                        const long s = sr[r];
                        const u16* dp = Dh + s * DD + lm * 6;
                        const u16* bp = Bh + s * DD + lm * 6;
                        gd[r * 3 + 0] = *(const u32*)dp;
                        gd[r * 3 + 1] = *(const u32*)(dp + 2);
                        gd[r * 3 + 2] = *(const u32*)(dp + 4);
                        gb[r * 3 + 0] = *(const u32*)bp;
                        gb[r * 3 + 1] = *(const u32*)(bp + 2);
                        gb[r * 3 + 2] = *(const u32*)(bp + 4);
                    }
                }
                __builtin_amdgcn_sched_barrier(0);   // pin: all gathers issued before epilogue
                // epilogue: row = quad*4+r; lane owns stored cols lm*6..lm*6+5
#pragma unroll
                for (int r = 0; r < 4; ++r) {
                    const int rl = quad * 4 + r;
                    if (rl < rows) {
                        u16* ep = ebuf + (long)(chunk + rl) * DD + lm * 6;
                        u32 o0 = *(const u32*)ep, o1 = *(const u32*)(ep + 2), o2 = *(const u32*)(ep + 4);
                        float dh[6] = {unlo(gd[r * 3]), unhi(gd[r * 3]), unlo(gd[r * 3 + 1]),
                                       unhi(gd[r * 3 + 1]), unlo(gd[r * 3 + 2]), unhi(gd[r * 3 + 2])};
                        float bh[6] = {unlo(gb[r * 3]), unhi(gb[r * 3]), unlo(gb[r * 3 + 1]),
                                       unhi(gb[r * 3 + 1]), unlo(gb[r * 3 + 2]), unhi(gb[r * 3 + 2])};
                        float od[6] = {unlo(o0), unhi(o0), unlo(o1), unhi(o1), unlo(o2), unhi(o2)};
                        float ov[6];
#pragma unroll
                        for (int t = 0; t < 6; ++t) {
                            float en = acc[t][r] + dh[t] + eh[t];
                            float sg = frcp(1.f + __expf(-en));
                            nacc[t] += bh[t] * sg;
                            dacc[t] += sg;
                            ov[t] = od[t] + fmaxf(en, 0.f);
                        }
                        *(u32*)ep       = pk2(ov[0], ov[1]);
                        *(u32*)(ep + 2) = pk2(ov[2], ov[3]);
                        *(u32*)(ep + 4) = pk2(ov[4], ov[5]);
                    }
                }
#pragma unroll
                for (int r = 0; r < 4; ++r) sr[r] = srn[r];
            }
        }
        // reduce over quads (butterfly across lane bits 4-5)
#pragma unroll
        for (int t = 0; t < 6; ++t) {
            float x = nacc[t], y = dacc[t];
            x += __shfl_xor(x, 16); y += __shfl_xor(y, 16);
            x += __shfl_xor(x, 32); y += __shfl_xor(y, 32);
            nacc[t] = x; dacc[t] = y;
        }
        if (quad == 0) {
            const float* ap = Ah + (long)n * DD + lm * 6;
            float* hp = hbuf + (long)n * DD + lm * 6;
            float val[6];
#pragma unroll
            for (int t = 0; t < 6; ++t)
                val[t] = fmaxf(ap[t] + nacc[t] * frcp(dacc[t] + EPSF), 0.f);
            float2 h0 = *(float2*)hp, h1 = *(float2*)(hp + 2), h2 = *(float2*)(hp + 4);
            *(float2*)(hp)     = make_float2(h0.x + val[0], h0.y + val[1]);
            *(float2*)(hp + 2) = make_float2(h1.x + val[2], h1.y + val[3]);
            *(float2*)(hp + 4) = make_float2(h2.x + val[4], h2.y + val[5]);
        }
    }
}

// small MLP stage, one thread per output element
__global__ void k_mlp(const float* __restrict__ X, const float* __restrict__ W,
                      const float* __restrict__ B, float* __restrict__ Y,
                      int K, int Dout, int act, long total) {
    long idx = (long)blockIdx.x * blockDim.x + threadIdx.x;
    if (idx >= total) return;
    int row = (int)(idx / Dout);
    int j = (int)(idx - (long)row * Dout);
    const float* xr = X + (long)row * K;
    float acc = B[j];
    for (int k = 0; k < K; ++k) acc = fmaf(xr[k], W[k * Dout + j], acc);
    if (act == 1) acc = fmaxf(acc, 0.f);
    else if (act == 2) acc = frcp(1.f + __expf(-acc));
    Y[idx] = acc;
}

extern "C" void kernel_launch(void* const* d_in, const int* in_sizes, int n_in,
                              void* d_out, int out_size, void* d_ws, size_t ws_size,
                              hipStream_t stream) {
    const float* h_in = (const float*)d_in[0];
    const float* e_in = (const float*)d_in[1];
    const int* src = (const int*)d_in[2];
    const int* dst = (const int*)d_in[3];
    const float* fp_w = (const float*)d_in[4];
    const float* fp_b = (const float*)d_in[5];
    const float* ep_w = (const float*)d_in[6];
    const float* ep_b = (const float*)d_in[7];
    const float* A_w = (const float*)d_in[8];
    const float* A_b = (const float*)d_in[9];
    const float* B_w = (const float*)d_in[10];
    const float* B_b = (const float*)d_in[11];
    const float* C_w = (const float*)d_in[12];
    const float* C_b = (const float*)d_in[13];
    const float* D_w = (const float*)d_in[14];
    const float* D_b = (const float*)d_in[15];
    const float* E_w = (const float*)d_in[16];
    const float* E_b = (const float*)d_in[17];
    const float* mlp0_w = (const float*)d_in[18];
    const float* mlp0_b = (const float*)d_in[19];
    const float* mlp1_w = (const float*)d_in[20];
    const float* mlp1_b = (const float*)d_in[21];
    const float* mlp2_w = (const float*)d_in[22];
    const float* mlp2_b = (const float*)d_in[23];
    float* out = (float*)d_out;

    const size_t ND_ = (size_t)NN * DD;
    const size_t ED_ = (size_t)NE * DD;
    const size_t FRAG = (size_t)NL * 6 * 3 * 64 * 8;   // u16 count per packed tensor
    char* w = (char*)d_ws;
    float* hbuf = (float*)w; w += ND_ * 4;
    float* Ahb  = (float*)w; w += ND_ * 4;
    u16* Bhb = (u16*)w; w += ND_ * 2;
    u16* Dhb = (u16*)w; w += ND_ * 2;
    u16* Ehb = (u16*)w; w += ND_ * 2;
    u16* ebuf = (u16*)w; w += ED_ * 2;
    int* counts  = (int*)w; w += (size_t)NN * 4;
    int* cursor  = (int*)w; w += (size_t)NN * 4;
    int* row_ptr = (int*)w; w += (size_t)(NN + 1) * 4 + 12;
    int* bsum    = (int*)w; w += 256;
    int* eperm   = (int*)w; w += (size_t)NE * 4;
    int* srcp    = (int*)w; w += (size_t)NE * 4;
    u16* awf = (u16*)w; w += FRAG * 2;
    u16* bwf = (u16*)w; w += FRAG * 2;
    u16* cwf = (u16*)w; w += FRAG * 2;
    u16* dwf = (u16*)w; w += FRAG * 2;
    u16* ewf = (u16*)w; w += FRAG * 2;
    u16* wfp = (u16*)w; w += (size_t)6 * 64 * 8 * 2;
    u16* wep = (u16*)w; w += (size_t)6 * 64 * 8 * 2;
    float* w0p = (float*)w; w += (size_t)DD * 48 * 4;
    size_t need = (size_t)(w - (char*)d_ws);
    if (ws_size < need) return;  // uniform -> graph-safe; fails absmax as diagnostic

    // CSR build (dst-sorted edge permutation), multi-block scan
    k_zero4<<<(NN / 4 + 255) / 256, 256, 0, stream>>>(counts, NN / 4);
    k_hist<<<(NE + 255) / 256, 256, 0, stream>>>(dst, counts);
    const int nsb = (NN + 1023) / 1024;
    k_scan1<<<nsb, 1024, 0, stream>>>(counts, row_ptr, bsum, NN);
    k_scan2<<<1, 64, 0, stream>>>(bsum, nsb);
    k_scan3<<<(NN + 255) / 256, 256, 0, stream>>>(row_ptr, cursor, bsum, NN);
    k_scatter<<<(NE + 255) / 256, 256, 0, stream>>>(src, dst, cursor, eperm, srcp);

    // fused weight packing (all layer weights k-permuted; projections canonical)
    const int packTot = 5 * (NL * 6 * 3 * 64) + 768 + DD * 48;
    k_packAll<<<(packTot + 255) / 256, 256, 0, stream>>>(A_w, B_w, C_w, D_w, E_w,
                                                         fp_w, ep_w, mlp0_w,
                                                         awf, bwf, cwf, dwf, ewf,
                                                         wfp, wep, w0p);

    // input projections (h f32 permuted; e bf16 permuted, dst-sorted)
    k_proj_m<false, false, true><<<256, 256, 0, stream>>>(h_in, wfp, fp_b, hbuf, nullptr, NN / 16);
    k_proj_m<true, true, true><<<2048, 256, 0, stream>>>(e_in, wep, ep_b, ebuf, eperm, NE / 16);

    const size_t LFRAG = (size_t)6 * 3 * 64 * 8;
    for (int l = 0; l < NL; ++l) {
        const float* Ab = A_b + (size_t)l * DD;
        const float* Bb = B_b + (size_t)l * DD;
        const float* Cb = C_b + (size_t)l * DD;
        const float* Db = D_b + (size_t)l * DD;
        const float* Eb = E_b + (size_t)l * DD;

        k_gemm4m<<<1280, 256, 0, stream>>>(hbuf,
                                           awf + l * LFRAG, Ab, bwf + l * LFRAG, Bb,
                                           dwf + l * LFRAG, Db, ewf + l * LFRAG, Eb,
                                           Ahb, Bhb, Dhb, Ehb, NN / 16);
        k_node_edge_w<<<2560, 256, 0, stream>>>(ebuf, cwf + l * LFRAG, Cb, Dhb, Ehb, Bhb,
                                                srcp, row_ptr, Ahb, hbuf);
    }

    // MLP readout: 96 -> 48 (relu) -> 24 (relu) -> 10 (sigmoid). Reuse Ahb as temps.
    // Stage 0 uses the permuted-row weight copy (hbuf is in permuted basis).
    float* y1 = Ahb;
    float* y2 = Ahb + (size_t)NN * 48;
    long t0 = (long)NN * 48, t1 = (long)NN * 24, t2 = (long)NN * NCLS;
    k_mlp<<<(int)((t0 + 255) / 256), 256, 0, stream>>>(hbuf, w0p, mlp0_b, y1, DD, 48, 1, t0);
    k_mlp<<<(int)((t1 + 255) / 256), 256, 0, stream>>>(y1, mlp1_w, mlp1_b, y2, 48, 24, 1, t1);
    k_mlp<<<(int)((t2 + 255) / 256), 256, 0, stream>>>(y2, mlp2_w, mlp2_b, out, 24, NCLS, 2, t2);
}

// Round 6
// 1221.530 us; speedup vs baseline: 2.0960x; 1.4418x over previous
//
#include <hip/hip_runtime.h>

#define NN 50000
#define NE 800000
#define DIN 32
#define DD 96
#define NL 4
#define NCLS 10
#define EPSF 1e-6f

typedef unsigned short u16;
typedef unsigned int u32;

typedef __bf16 bf16x8 __attribute__((ext_vector_type(8)));
typedef float f32x4 __attribute__((ext_vector_type(4)));

static __device__ __forceinline__ u16 f2bf(float f) {
    u32 x = __float_as_uint(f);
    x += 0x7FFFu + ((x >> 16) & 1u);   // round-to-nearest-even
    return (u16)(x >> 16);
}
// packed RNE f32x2 -> bf16x2 in one instruction (gfx950)
static __device__ __forceinline__ u32 pk2(float a, float b) {
    u32 r;
    asm("v_cvt_pk_bf16_f32 %0, %1, %2" : "=v"(r) : "v"(a), "v"(b));
    return r;
}
static __device__ __forceinline__ float unlo(u32 u) { return __uint_as_float(u << 16); }
static __device__ __forceinline__ float unhi(u32 u) { return __uint_as_float(u & 0xFFFF0000u); }
static __device__ __forceinline__ float frcp(float x) { return __builtin_amdgcn_rcpf(x); }

__global__ void k_zero4(int* __restrict__ p, long n4) {
    long i = (long)blockIdx.x * blockDim.x + threadIdx.x;
    if (i < n4) ((int4*)p)[i] = make_int4(0, 0, 0, 0);
}

__global__ void k_hist(const int* __restrict__ dst, int* __restrict__ counts) {
    int i = blockIdx.x * blockDim.x + threadIdx.x;
    if (i < NE) atomicAdd(&counts[dst[i]], 1);
}

// multi-block scan, pass 1: per-block local exclusive scan + block sums
__global__ __launch_bounds__(1024) void k_scan1(const int* __restrict__ counts,
                                                int* __restrict__ excl,
                                                int* __restrict__ bsum, int n) {
    __shared__ int wsum[16];
    const int tid = threadIdx.x, lane = tid & 63, wid = tid >> 6;
    const int i = blockIdx.x * 1024 + tid;
    int v = (i < n) ? counts[i] : 0;
    int x = v;
#pragma unroll
    for (int off = 1; off < 64; off <<= 1) {
        int t = __shfl_up(x, (unsigned)off, 64);
        if (lane >= off) x += t;
    }
    if (lane == 63) wsum[wid] = x;
    __syncthreads();
    if (tid < 16) {
        int s = wsum[tid];
#pragma unroll
        for (int off = 1; off < 16; off <<= 1) {
            int t = __shfl_up(s, (unsigned)off, 16);
            if (tid >= off) s += t;
        }
        wsum[tid] = s;
    }
    __syncthreads();
    const int wbase = wid ? wsum[wid - 1] : 0;
    if (i < n) excl[i] = wbase + x - v;
    if (tid == 1023) bsum[blockIdx.x] = wbase + x;
}

// pass 2: exclusive scan of block sums (<=64 blocks), single wave
__global__ void k_scan2(int* __restrict__ bsum, int nb) {
    const int lane = threadIdx.x;
    int v = (lane < nb) ? bsum[lane] : 0;
    int x = v;
#pragma unroll
    for (int off = 1; off < 64; off <<= 1) {
        int t = __shfl_up(x, (unsigned)off, 64);
        if (lane >= off) x += t;
    }
    if (lane < nb) bsum[lane] = x - v;
}

// pass 3: add block offsets -> final row_ptr and cursor copy; row_ptr[n]=NE.
__global__ void k_scan3(int* __restrict__ row_ptr, int* __restrict__ cursor,
                        const int* __restrict__ bsum, int n) {
    int i = blockIdx.x * blockDim.x + threadIdx.x;
    if (i < n) {
        int v = row_ptr[i] + bsum[i >> 10];
        row_ptr[i] = v;
        cursor[i] = v;
    }
    if (i == 0) row_ptr[n] = NE;
}

__global__ void k_scatter(const int* __restrict__ src, const int* __restrict__ dst,
                          int* __restrict__ cursor, int* __restrict__ eperm,
                          int* __restrict__ srcp) {
    int i = blockIdx.x * blockDim.x + threadIdx.x;
    if (i >= NE) return;
    int pos = atomicAdd(&cursor[dst[i]], 1);
    eperm[pos] = i;
    srcp[pos] = src[i];
}

// Fused packer: 5x [NL][96][96] layer weights (all k-permuted: both h-state and
// e-state live in the permuted basis), 2x [32,96] projections (canonical k),
// and the permuted-row copy of mlp0_w.
__global__ void k_packAll(const float* __restrict__ A_w, const float* __restrict__ B_w,
                          const float* __restrict__ C_w, const float* __restrict__ D_w,
                          const float* __restrict__ E_w,
                          const float* __restrict__ fp_w, const float* __restrict__ ep_w,
                          const float* __restrict__ m0w,
                          u16* __restrict__ awf, u16* __restrict__ bwf, u16* __restrict__ cwf,
                          u16* __restrict__ dwf, u16* __restrict__ ewf,
                          u16* __restrict__ wfp, u16* __restrict__ wep,
                          float* __restrict__ w0p) {
    const int PER = NL * 6 * 3 * 64;   // 4608 fragments per tensor
    int q = blockIdx.x * blockDim.x + threadIdx.x;
    if (q < 5 * PER) {
        int which = q / PER;
        int qq = q - which * PER;
        const float* W_all = which == 0 ? A_w : which == 1 ? B_w : which == 2 ? C_w
                           : which == 3 ? D_w : E_w;
        u16* wf = which == 0 ? awf : which == 1 ? bwf : which == 2 ? cwf
                : which == 3 ? dwf : ewf;
        int l = qq / (6 * 3 * 64);
        int rem = qq - l * (6 * 3 * 64);
        int tile = rem / (3 * 64);
        int rem2 = rem - tile * (3 * 64);
        int c = rem2 >> 6, ln = rem2 & 63;
        const float* W = W_all + (long)l * DD * DD;
        int n = tile * 16 + (ln & 15);
        int k0 = c * 32 + (ln >> 4) * 8;
        u16 wv[8];
#pragma unroll
        for (int j = 0; j < 8; ++j) {
            int kk = k0 + j;
            int kact = (kk % 6) * 16 + kk / 6;   // stored-p -> actual feature
            wv[j] = f2bf(W[kact * DD + n]);
        }
        *(uint4*)&wf[(long)qq * 8] = *(uint4*)wv;
    } else if (q < 5 * PER + 768) {
        int qq = q - 5 * PER;
        int which = qq / 384; qq -= which * 384;
        const float* W = which ? ep_w : fp_w;
        u16* wf = which ? wep : wfp;
        int ln = qq & 63;
        int n = (qq >> 6) * 16 + (ln & 15);
        int k0 = (ln >> 4) * 8;
        u16 wv[8];
#pragma unroll
        for (int j = 0; j < 8; ++j) wv[j] = f2bf(W[(k0 + j) * DD + n]);
        *(uint4*)&wf[qq * 8] = *(uint4*)wv;
    } else {
        int qq = q - 5 * PER - 768;
        if (qq < DD * 48) {
            int p = qq / 48, j = qq - p * 48;
            int jp = (p % 6) * 16 + p / 6;       // actual feature of stored p
            w0p[qq] = m0w[jp * 48 + j];
        }
    }
}

// Barrier-free MFMA input projection: one wave per 16-row tile, grid-stride.
// POUT: permuted-basis output (stored p = lm*6+t holds actual col t*16+lm).
// BFOUT selects bf16 (3x u32) vs f32 (3x float2) stores on the POUT path.
template <bool BFOUT, bool PERM, bool POUT>
__global__ __launch_bounds__(256) void k_proj_m(const float* __restrict__ X,
                                                const u16* __restrict__ wf,
                                                const float* __restrict__ B,
                                                void* __restrict__ Y,
                                                const int* __restrict__ eperm,
                                                int ntiles) {
    const int lane = threadIdx.x & 63;
    const int gw = (blockIdx.x * blockDim.x + threadIdx.x) >> 6;
    const int nw = (gridDim.x * blockDim.x) >> 6;
    const int lm = lane & 15, quad = lane >> 4;

    bf16x8 bfr[6];
    float bias[6];
#pragma unroll
    for (int t = 0; t < 6; ++t) {
        bfr[t] = *(const bf16x8*)&wf[(t * 64 + lane) * 8];
        bias[t] = B[t * 16 + lm];
    }

    for (int tile = gw; tile < ntiles; tile += nw) {
        const int row = tile * 16 + lm;
        const long srow = PERM ? (long)eperm[row] : (long)row;
        float4 x0 = *(const float4*)&X[srow * DIN + quad * 8];
        float4 x1 = *(const float4*)&X[srow * DIN + quad * 8 + 4];
        u32 ap[4] = {pk2(x0.x, x0.y), pk2(x0.z, x0.w), pk2(x1.x, x1.y), pk2(x1.z, x1.w)};
        bf16x8 af = *(bf16x8*)ap;
        f32x4 acc[6];
#pragma unroll
        for (int t = 0; t < 6; ++t) {
            acc[t] = (f32x4){bias[t], bias[t], bias[t], bias[t]};
            acc[t] = __builtin_amdgcn_mfma_f32_16x16x32_bf16(af, bfr[t], acc[t], 0, 0, 0);
        }
        const long rbase = (long)tile * 16 + quad * 4;
        if (POUT) {
#pragma unroll
            for (int r = 0; r < 4; ++r) {
                if (BFOUT) {
                    u16* p = (u16*)Y + (rbase + r) * DD + lm * 6;
                    *(u32*)p       = pk2(acc[0][r], acc[1][r]);
                    *(u32*)(p + 2) = pk2(acc[2][r], acc[3][r]);
                    *(u32*)(p + 4) = pk2(acc[4][r], acc[5][r]);
                } else {
                    float* p = (float*)Y + (rbase + r) * DD + lm * 6;
                    *(float2*)(p)     = make_float2(acc[0][r], acc[1][r]);
                    *(float2*)(p + 2) = make_float2(acc[2][r], acc[3][r]);
                    *(float2*)(p + 4) = make_float2(acc[4][r], acc[5][r]);
                }
            }
        } else {
#pragma unroll
            for (int t = 0; t < 6; ++t) {
                const int j = t * 16 + lm;
#pragma unroll
                for (int r = 0; r < 4; ++r) {
                    float v = acc[t][r];
                    if (BFOUT) ((u16*)Y)[(rbase + r) * DD + j] = f2bf(v);
                    else       ((float*)Y)[(rbase + r) * DD + j] = v;
                }
            }
        }
    }
}

// Barrier-free MFMA 4-way node GEMM: wave w of each block handles matrix w.
// All outputs in permuted basis: A -> f32 (3x float2), B/D/E -> bf16 (3x u32).
__global__ __launch_bounds__(256) void k_gemm4m(const float* __restrict__ X,
                                                const u16* __restrict__ awf, const float* __restrict__ ab,
                                                const u16* __restrict__ bwf, const float* __restrict__ bb,
                                                const u16* __restrict__ dwf, const float* __restrict__ db,
                                                const u16* __restrict__ ewf, const float* __restrict__ eb,
                                                float* __restrict__ Y0, u16* __restrict__ Y1,
                                                u16* __restrict__ Y2, u16* __restrict__ Y3,
                                                int ntiles) {
    const int lane = threadIdx.x & 63;
    const int w = threadIdx.x >> 6;   // matrix 0..3
    const int lm = lane & 15, quad = lane >> 4;
    const u16* wf = (w == 0) ? awf : (w == 1) ? bwf : (w == 2) ? dwf : ewf;
    const float* bp = (w == 0) ? ab : (w == 1) ? bb : (w == 2) ? db : eb;

    bf16x8 bfr[6][3];
    float bias[6];
#pragma unroll
    for (int t = 0; t < 6; ++t) {
#pragma unroll
        for (int c = 0; c < 3; ++c)
            bfr[t][c] = *(const bf16x8*)&wf[((t * 3 + c) * 64 + lane) * 8];
        bias[t] = bp[t * 16 + lm];
    }

    for (int tile = blockIdx.x; tile < ntiles; tile += gridDim.x) {
        const float* xr = X + (long)(tile * 16 + lm) * DD;
        bf16x8 a[3];
#pragma unroll
        for (int c = 0; c < 3; ++c) {
            float4 x0 = *(const float4*)&xr[c * 32 + quad * 8];
            float4 x1 = *(const float4*)&xr[c * 32 + quad * 8 + 4];
            u32 ap[4] = {pk2(x0.x, x0.y), pk2(x0.z, x0.w), pk2(x1.x, x1.y), pk2(x1.z, x1.w)};
            a[c] = *(bf16x8*)ap;
        }
        f32x4 acc[6];
#pragma unroll
        for (int t = 0; t < 6; ++t) {
            acc[t] = (f32x4){bias[t], bias[t], bias[t], bias[t]};
#pragma unroll
            for (int c = 0; c < 3; ++c)
                acc[t] = __builtin_amdgcn_mfma_f32_16x16x32_bf16(a[c], bfr[t][c], acc[t], 0, 0, 0);
        }
        const long rbase = (long)tile * 16 + quad * 4;
        if (w == 0) {
#pragma unroll
            for (int r = 0; r < 4; ++r) {
                float* p = Y0 + (rbase + r) * DD + lm * 6;
                *(float2*)(p)     = make_float2(acc[0][r], acc[1][r]);
                *(float2*)(p + 2) = make_float2(acc[2][r], acc[3][r]);
                *(float2*)(p + 4) = make_float2(acc[4][r], acc[5][r]);
            }
        } else {
            u16* Yp = (w == 1) ? Y1 : (w == 2) ? Y2 : Y3;
#pragma unroll
            for (int r = 0; r < 4; ++r) {
                u16* p = Yp + (rbase + r) * DD + lm * 6;
                *(u32*)p       = pk2(acc[0][r], acc[1][r]);
                *(u32*)(p + 2) = pk2(acc[2][r], acc[3][r]);
                *(u32*)(p + 4) = pk2(acc[4][r], acc[5][r]);
            }
        }
    }
}

// Barrier-free, LDS-free, atomic-free fused edge+aggregate: one wave per node
// (grid-stride). R2 structure (VGPR<=128, 4 waves/SIMD) + ONE new lever:
// next-chunk srcp values prefetched one iteration ahead (+4 VGPR), breaking
// the per-chunk serial chain srcp-load(~300cy) -> dependent gather(~900cy).
// Gathers themselves stay compiler-scheduled (Dh/Bh are __restrict const, the
// compiler already hoists them above the epilogue compute). eh folded into
// the MFMA C-init (cb+eh), removing 24 VALU adds per chunk.
__global__ __launch_bounds__(256) void k_node_edge_w(u16* ebuf,
                                                     const u16* __restrict__ cwf,  // k-permuted pack
                                                     const float* __restrict__ Cb,
                                                     const u16* __restrict__ Dh,
                                                     const u16* __restrict__ Eh,
                                                     const u16* __restrict__ Bh,
                                                     const int* __restrict__ srcp,
                                                     const int* __restrict__ row_ptr,
                                                     const float* __restrict__ Ah,
                                                     float* __restrict__ hbuf) {
    const int lane = threadIdx.x & 63;
    const int gw = (blockIdx.x * blockDim.x + threadIdx.x) >> 6;
    const int nw = (gridDim.x * blockDim.x) >> 6;
    const int lm = lane & 15, quad = lane >> 4;

    bf16x8 bfrag[6][3];
    float cb[6];
#pragma unroll
    for (int t = 0; t < 6; ++t) {
#pragma unroll
        for (int c = 0; c < 3; ++c)
            bfrag[t][c] = *(const bf16x8*)&cwf[((t * 3 + c) * 64 + lane) * 8];
        cb[t] = Cb[t * 16 + lm];   // stored p=lm*6+t <-> actual col t*16+lm
    }

    for (int n = gw; n < NN; n += nw) {
        const int r0 = row_ptr[n], r1 = row_ptr[n + 1];
        float nacc[6] = {0.f, 0.f, 0.f, 0.f, 0.f, 0.f};
        float dacc[6] = {0.f, 0.f, 0.f, 0.f, 0.f, 0.f};

        if (r0 < r1) {
            // ehc = Cb + Eh[n] (both constant over this node's rows) -> MFMA C-init
            float ehc[6];
            {
                const u16* ep = Eh + (long)n * DD + lm * 6;
                u32 e0 = *(const u32*)ep, e1 = *(const u32*)(ep + 2), e2 = *(const u32*)(ep + 4);
                ehc[0] = cb[0] + unlo(e0); ehc[1] = cb[1] + unhi(e0);
                ehc[2] = cb[2] + unlo(e1); ehc[3] = cb[3] + unhi(e1);
                ehc[4] = cb[4] + unlo(e2); ehc[5] = cb[5] + unhi(e2);
            }
            // preload first chunk's A-fragments + srcp
            bf16x8 a[3];
            {
                const int rows = r1 - r0 < 16 ? r1 - r0 : 16;
                const long arow = r0 + (lm < rows ? lm : 0);
#pragma unroll
                for (int c = 0; c < 3; ++c)
                    a[c] = *(const bf16x8*)&ebuf[arow * DD + c * 32 + quad * 8];
            }
            int sr[4];
#pragma unroll
            for (int r = 0; r < 4; ++r) {
                const int rl = quad * 4 + r;
                sr[r] = (r0 + rl < r1) ? srcp[r0 + rl] : 0;
            }

            for (int chunk = r0; chunk < r1; chunk += 16) {
                const int rows = r1 - chunk < 16 ? r1 - chunk : 16;
                f32x4 acc[6];
#pragma unroll
                for (int t = 0; t < 6; ++t) {
                    acc[t] = (f32x4){ehc[t], ehc[t], ehc[t], ehc[t]};
#pragma unroll
                    for (int c = 0; c < 3; ++c)
                        acc[t] = __builtin_amdgcn_mfma_f32_16x16x32_bf16(a[c], bfrag[t][c], acc[t], 0, 0, 0);
                }
                // prefetch next chunk's A-fragments + srcp (consumed next iter:
                // the srcp->gather address chain moves off the critical path)
                const int nchunk = chunk + 16;
                int srn[4] = {0, 0, 0, 0};
                if (nchunk < r1) {
                    const int rows2 = r1 - nchunk < 16 ? r1 - nchunk : 16;
                    const long arow2 = nchunk + (lm < rows2 ? lm : 0);
#pragma unroll
                    for (int c = 0; c < 3; ++c)
                        a[c] = *(const bf16x8*)&ebuf[arow2 * DD + c * 32 + quad * 8];
#pragma unroll
                    for (int r = 0; r < 4; ++r) {
                        const int rl = quad * 4 + r;
                        if (nchunk + rl < r1) srn[r] = srcp[nchunk + rl];
                    }
                }
                // epilogue: row = quad*4+r; lane owns stored cols lm*6..lm*6+5
#pragma unroll
                for (int r = 0; r < 4; ++r) {
                    const int rl = quad * 4 + r;
                    if (rl < rows) {
                        const long s = sr[r];
                        const u16* dp = Dh + s * DD + lm * 6;
                        const u16* bp = Bh + s * DD + lm * 6;
                        u16* ep = ebuf + (long)(chunk + rl) * DD + lm * 6;
                        u32 d0 = *(const u32*)dp, d1 = *(const u32*)(dp + 2), d2 = *(const u32*)(dp + 4);
                        u32 b0 = *(const u32*)bp, b1 = *(const u32*)(bp + 2), b2 = *(const u32*)(bp + 4);
                        u32 o0 = *(const u32*)ep, o1 = *(const u32*)(ep + 2), o2 = *(const u32*)(ep + 4);
                        float dh[6] = {unlo(d0), unhi(d0), unlo(d1), unhi(d1), unlo(d2), unhi(d2)};
                        float bh[6] = {unlo(b0), unhi(b0), unlo(b1), unhi(b1), unlo(b2), unhi(b2)};
                        float od[6] = {unlo(o0), unhi(o0), unlo(o1), unhi(o1), unlo(o2), unhi(o2)};
                        float ov[6];
#pragma unroll
                        for (int t = 0; t < 6; ++t) {
                            float en = acc[t][r] + dh[t];
                            float sg = frcp(1.f + __expf(-en));
                            nacc[t] += bh[t] * sg;
                            dacc[t] += sg;
                            ov[t] = od[t] + fmaxf(en, 0.f);
                        }
                        *(u32*)ep       = pk2(ov[0], ov[1]);
                        *(u32*)(ep + 2) = pk2(ov[2], ov[3]);
                        *(u32*)(ep + 4) = pk2(ov[4], ov[5]);
                    }
                }
#pragma unroll
                for (int r = 0; r < 4; ++r) sr[r] = srn[r];
            }
        }
        // reduce over quads (butterfly across lane bits 4-5)
#pragma unroll
        for (int t = 0; t < 6; ++t) {
            float x = nacc[t], y = dacc[t];
            x += __shfl_xor(x, 16); y += __shfl_xor(y, 16);
            x += __shfl_xor(x, 32); y += __shfl_xor(y, 32);
            nacc[t] = x; dacc[t] = y;
        }
        if (quad == 0) {
            const float* ap = Ah + (long)n * DD + lm * 6;
            float* hp = hbuf + (long)n * DD + lm * 6;
            float val[6];
#pragma unroll
            for (int t = 0; t < 6; ++t)
                val[t] = fmaxf(ap[t] + nacc[t] * frcp(dacc[t] + EPSF), 0.f);
            float2 h0 = *(float2*)hp, h1 = *(float2*)(hp + 2), h2 = *(float2*)(hp + 4);
            *(float2*)(hp)     = make_float2(h0.x + val[0], h0.y + val[1]);
            *(float2*)(hp + 2) = make_float2(h1.x + val[2], h1.y + val[3]);
            *(float2*)(hp + 4) = make_float2(h2.x + val[4], h2.y + val[5]);
        }
    }
}

// small MLP stage, one thread per output element
__global__ void k_mlp(const float* __restrict__ X, const float* __restrict__ W,
                      const float* __restrict__ B, float* __restrict__ Y,
                      int K, int Dout, int act, long total) {
    long idx = (long)blockIdx.x * blockDim.x + threadIdx.x;
    if (idx >= total) return;
    int row = (int)(idx / Dout);
    int j = (int)(idx - (long)row * Dout);
    const float* xr = X + (long)row * K;
    float acc = B[j];
    for (int k = 0; k < K; ++k) acc = fmaf(xr[k], W[k * Dout + j], acc);
    if (act == 1) acc = fmaxf(acc, 0.f);
    else if (act == 2) acc = frcp(1.f + __expf(-acc));
    Y[idx] = acc;
}

extern "C" void kernel_launch(void* const* d_in, const int* in_sizes, int n_in,
                              void* d_out, int out_size, void* d_ws, size_t ws_size,
                              hipStream_t stream) {
    const float* h_in = (const float*)d_in[0];
    const float* e_in = (const float*)d_in[1];
    const int* src = (const int*)d_in[2];
    const int* dst = (const int*)d_in[3];
    const float* fp_w = (const float*)d_in[4];
    const float* fp_b = (const float*)d_in[5];
    const float* ep_w = (const float*)d_in[6];
    const float* ep_b = (const float*)d_in[7];
    const float* A_w = (const float*)d_in[8];
    const float* A_b = (const float*)d_in[9];
    const float* B_w = (const float*)d_in[10];
    const float* B_b = (const float*)d_in[11];
    const float* C_w = (const float*)d_in[12];
    const float* C_b = (const float*)d_in[13];
    const float* D_w = (const float*)d_in[14];
    const float* D_b = (const float*)d_in[15];
    const float* E_w = (const float*)d_in[16];
    const float* E_b = (const float*)d_in[17];
    const float* mlp0_w = (const float*)d_in[18];
    const float* mlp0_b = (const float*)d_in[19];
    const float* mlp1_w = (const float*)d_in[20];
    const float* mlp1_b = (const float*)d_in[21];
    const float* mlp2_w = (const float*)d_in[22];
    const float* mlp2_b = (const float*)d_in[23];
    float* out = (float*)d_out;

    const size_t ND_ = (size_t)NN * DD;
    const size_t ED_ = (size_t)NE * DD;
    const size_t FRAG = (size_t)NL * 6 * 3 * 64 * 8;   // u16 count per packed tensor
    char* w = (char*)d_ws;
    float* hbuf = (float*)w; w += ND_ * 4;
    float* Ahb  = (float*)w; w += ND_ * 4;
    u16* Bhb = (u16*)w; w += ND_ * 2;
    u16* Dhb = (u16*)w; w += ND_ * 2;
    u16* Ehb = (u16*)w; w += ND_ * 2;
    u16* ebuf = (u16*)w; w += ED_ * 2;
    int* counts  = (int*)w; w += (size_t)NN * 4;
    int* cursor  = (int*)w; w += (size_t)NN * 4;
    int* row_ptr = (int*)w; w += (size_t)(NN + 1) * 4 + 12;
    int* bsum    = (int*)w; w += 256;
    int* eperm   = (int*)w; w += (size_t)NE * 4;
    int* srcp    = (int*)w; w += (size_t)NE * 4;
    u16* awf = (u16*)w; w += FRAG * 2;
    u16* bwf = (u16*)w; w += FRAG * 2;
    u16* cwf = (u16*)w; w += FRAG * 2;
    u16* dwf = (u16*)w; w += FRAG * 2;
    u16* ewf = (u16*)w; w += FRAG * 2;
    u16* wfp = (u16*)w; w += (size_t)6 * 64 * 8 * 2;
    u16* wep = (u16*)w; w += (size_t)6 * 64 * 8 * 2;
    float* w0p = (float*)w; w += (size_t)DD * 48 * 4;
    size_t need = (size_t)(w - (char*)d_ws);
    if (ws_size < need) return;  // uniform -> graph-safe; fails absmax as diagnostic

    // CSR build (dst-sorted edge permutation), multi-block scan
    k_zero4<<<(NN / 4 + 255) / 256, 256, 0, stream>>>(counts, NN / 4);
    k_hist<<<(NE + 255) / 256, 256, 0, stream>>>(dst, counts);
    const int nsb = (NN + 1023) / 1024;
    k_scan1<<<nsb, 1024, 0, stream>>>(counts, row_ptr, bsum, NN);
    k_scan2<<<1, 64, 0, stream>>>(bsum, nsb);
    k_scan3<<<(NN + 255) / 256, 256, 0, stream>>>(row_ptr, cursor, bsum, NN);
    k_scatter<<<(NE + 255) / 256, 256, 0, stream>>>(src, dst, cursor, eperm, srcp);

    // fused weight packing (all layer weights k-permuted; projections canonical)
    const int packTot = 5 * (NL * 6 * 3 * 64) + 768 + DD * 48;
    k_packAll<<<(packTot + 255) / 256, 256, 0, stream>>>(A_w, B_w, C_w, D_w, E_w,
                                                         fp_w, ep_w, mlp0_w,
                                                         awf, bwf, cwf, dwf, ewf,
                                                         wfp, wep, w0p);

    // input projections (h f32 permuted; e bf16 permuted, dst-sorted)
    k_proj_m<false, false, true><<<256, 256, 0, stream>>>(h_in, wfp, fp_b, hbuf, nullptr, NN / 16);
    k_proj_m<true, true, true><<<2048, 256, 0, stream>>>(e_in, wep, ep_b, ebuf, eperm, NE / 16);

    const size_t LFRAG = (size_t)6 * 3 * 64 * 8;
    for (int l = 0; l < NL; ++l) {
        const float* Ab = A_b + (size_t)l * DD;
        const float* Bb = B_b + (size_t)l * DD;
        const float* Cb = C_b + (size_t)l * DD;
        const float* Db = D_b + (size_t)l * DD;
        const float* Eb = E_b + (size_t)l * DD;

        k_gemm4m<<<1280, 256, 0, stream>>>(hbuf,
                                           awf + l * LFRAG, Ab, bwf + l * LFRAG, Bb,
                                           dwf + l * LFRAG, Db, ewf + l * LFRAG, Eb,
                                           Ahb, Bhb, Dhb, Ehb, NN / 16);
        k_node_edge_w<<<2560, 256, 0, stream>>>(ebuf, cwf + l * LFRAG, Cb, Dhb, Ehb, Bhb,
                                                srcp, row_ptr, Ahb, hbuf);
    }

    // MLP readout: 96 -> 48 (relu) -> 24 (relu) -> 10 (sigmoid). Reuse Ahb as temps.
    // Stage 0 uses the permuted-row weight copy (hbuf is in permuted basis).
    float* y1 = Ahb;
    float* y2 = Ahb + (size_t)NN * 48;
    long t0 = (long)NN * 48, t1 = (long)NN * 24, t2 = (long)NN * NCLS;
    k_mlp<<<(int)((t0 + 255) / 256), 256, 0, stream>>>(hbuf, w0p, mlp0_b, y1, DD, 48, 1, t0);
    k_mlp<<<(int)((t1 + 255) / 256), 256, 0, stream>>>(y1, mlp1_w, mlp1_b, y2, 48, 24, 1, t1);
    k_mlp<<<(int)((t2 + 255) / 256), 256, 0, stream>>>(y2, mlp2_w, mlp2_b, out, 24, NCLS, 2, t2);
}

// Round 7
// 1169.718 us; speedup vs baseline: 2.1889x; 1.0443x over previous
//
#include <hip/hip_runtime.h>

#define NN 50000
#define NE 800000
#define DIN 32
#define DD 96
#define NL 4
#define NCLS 10
#define EPSF 1e-6f

typedef unsigned short u16;
typedef unsigned int u32;

typedef __bf16 bf16x8 __attribute__((ext_vector_type(8)));
typedef float f32x4 __attribute__((ext_vector_type(4)));

static __device__ __forceinline__ u16 f2bf(float f) {
    u32 x = __float_as_uint(f);
    x += 0x7FFFu + ((x >> 16) & 1u);   // round-to-nearest-even
    return (u16)(x >> 16);
}
// packed RNE f32x2 -> bf16x2 in one instruction (gfx950)
static __device__ __forceinline__ u32 pk2(float a, float b) {
    u32 r;
    asm("v_cvt_pk_bf16_f32 %0, %1, %2" : "=v"(r) : "v"(a), "v"(b));
    return r;
}
static __device__ __forceinline__ float unlo(u32 u) { return __uint_as_float(u << 16); }
static __device__ __forceinline__ float unhi(u32 u) { return __uint_as_float(u & 0xFFFF0000u); }
static __device__ __forceinline__ float frcp(float x) { return __builtin_amdgcn_rcpf(x); }

__global__ void k_zero4(int* __restrict__ p, long n4) {
    long i = (long)blockIdx.x * blockDim.x + threadIdx.x;
    if (i < n4) ((int4*)p)[i] = make_int4(0, 0, 0, 0);
}

__global__ void k_hist(const int* __restrict__ dst, int* __restrict__ counts) {
    int i = blockIdx.x * blockDim.x + threadIdx.x;
    if (i < NE) atomicAdd(&counts[dst[i]], 1);
}

// multi-block scan, pass 1: per-block local exclusive scan + block sums
__global__ __launch_bounds__(1024) void k_scan1(const int* __restrict__ counts,
                                                int* __restrict__ excl,
                                                int* __restrict__ bsum, int n) {
    __shared__ int wsum[16];
    const int tid = threadIdx.x, lane = tid & 63, wid = tid >> 6;
    const int i = blockIdx.x * 1024 + tid;
    int v = (i < n) ? counts[i] : 0;
    int x = v;
#pragma unroll
    for (int off = 1; off < 64; off <<= 1) {
        int t = __shfl_up(x, (unsigned)off, 64);
        if (lane >= off) x += t;
    }
    if (lane == 63) wsum[wid] = x;
    __syncthreads();
    if (tid < 16) {
        int s = wsum[tid];
#pragma unroll
        for (int off = 1; off < 16; off <<= 1) {
            int t = __shfl_up(s, (unsigned)off, 16);
            if (tid >= off) s += t;
        }
        wsum[tid] = s;
    }
    __syncthreads();
    const int wbase = wid ? wsum[wid - 1] : 0;
    if (i < n) excl[i] = wbase + x - v;
    if (tid == 1023) bsum[blockIdx.x] = wbase + x;
}

// pass 2: exclusive scan of block sums (<=64 blocks), single wave
__global__ void k_scan2(int* __restrict__ bsum, int nb) {
    const int lane = threadIdx.x;
    int v = (lane < nb) ? bsum[lane] : 0;
    int x = v;
#pragma unroll
    for (int off = 1; off < 64; off <<= 1) {
        int t = __shfl_up(x, (unsigned)off, 64);
        if (lane >= off) x += t;
    }
    if (lane < nb) bsum[lane] = x - v;
}

// pass 3: add block offsets -> final row_ptr and cursor copy; row_ptr[n]=NE.
__global__ void k_scan3(int* __restrict__ row_ptr, int* __restrict__ cursor,
                        const int* __restrict__ bsum, int n) {
    int i = blockIdx.x * blockDim.x + threadIdx.x;
    if (i < n) {
        int v = row_ptr[i] + bsum[i >> 10];
        row_ptr[i] = v;
        cursor[i] = v;
    }
    if (i == 0) row_ptr[n] = NE;
}

// scatter: srcp in dst-sorted order; inv[orig edge] = sorted position
__global__ void k_scatter(const int* __restrict__ src, const int* __restrict__ dst,
                          int* __restrict__ cursor, int* __restrict__ inv,
                          int* __restrict__ srcp) {
    int i = blockIdx.x * blockDim.x + threadIdx.x;
    if (i >= NE) return;
    int pos = atomicAdd(&cursor[dst[i]], 1);
    inv[i] = pos;
    srcp[pos] = src[i];
}

// Fused packer: 5x [NL][96][96] layer weights (all k-permuted: both h-state and
// e-state live in the permuted basis), 2x [32,96] projections (canonical k),
// and the permuted-row copy of mlp0_w.
__global__ void k_packAll(const float* __restrict__ A_w, const float* __restrict__ B_w,
                          const float* __restrict__ C_w, const float* __restrict__ D_w,
                          const float* __restrict__ E_w,
                          const float* __restrict__ fp_w, const float* __restrict__ ep_w,
                          const float* __restrict__ m0w,
                          u16* __restrict__ awf, u16* __restrict__ bwf, u16* __restrict__ cwf,
                          u16* __restrict__ dwf, u16* __restrict__ ewf,
                          u16* __restrict__ wfp, u16* __restrict__ wep,
                          float* __restrict__ w0p) {
    const int PER = NL * 6 * 3 * 64;   // 4608 fragments per tensor
    int q = blockIdx.x * blockDim.x + threadIdx.x;
    if (q < 5 * PER) {
        int which = q / PER;
        int qq = q - which * PER;
        const float* W_all = which == 0 ? A_w : which == 1 ? B_w : which == 2 ? C_w
                           : which == 3 ? D_w : E_w;
        u16* wf = which == 0 ? awf : which == 1 ? bwf : which == 2 ? cwf
                : which == 3 ? dwf : ewf;
        int l = qq / (6 * 3 * 64);
        int rem = qq - l * (6 * 3 * 64);
        int tile = rem / (3 * 64);
        int rem2 = rem - tile * (3 * 64);
        int c = rem2 >> 6, ln = rem2 & 63;
        const float* W = W_all + (long)l * DD * DD;
        int n = tile * 16 + (ln & 15);
        int k0 = c * 32 + (ln >> 4) * 8;
        u16 wv[8];
#pragma unroll
        for (int j = 0; j < 8; ++j) {
            int kk = k0 + j;
            int kact = (kk % 6) * 16 + kk / 6;   // stored-p -> actual feature
            wv[j] = f2bf(W[kact * DD + n]);
        }
        *(uint4*)&wf[(long)qq * 8] = *(uint4*)wv;
    } else if (q < 5 * PER + 768) {
        int qq = q - 5 * PER;
        int which = qq / 384; qq -= which * 384;
        const float* W = which ? ep_w : fp_w;
        u16* wf = which ? wep : wfp;
        int ln = qq & 63;
        int n = (qq >> 6) * 16 + (ln & 15);
        int k0 = (ln >> 4) * 8;
        u16 wv[8];
#pragma unroll
        for (int j = 0; j < 8; ++j) wv[j] = f2bf(W[(k0 + j) * DD + n]);
        *(uint4*)&wf[qq * 8] = *(uint4*)wv;
    } else {
        int qq = q - 5 * PER - 768;
        if (qq < DD * 48) {
            int p = qq / 48, j = qq - p * 48;
            int jp = (p % 6) * 16 + p / 6;       // actual feature of stored p
            w0p[qq] = m0w[jp * 48 + j];
        }
    }
}

// Barrier-free MFMA input projection: one wave per 16-row tile, grid-stride.
// POUT: permuted-basis output (stored p = lm*6+t holds actual col t*16+lm).
// SCAT: sequential input rows, output row scattered via rmap (inverse perm) --
// randomness on the store side (fire-and-forget) instead of the load side.
template <bool BFOUT, bool POUT, bool SCAT>
__global__ __launch_bounds__(256) void k_proj_m(const float* __restrict__ X,
                                                const u16* __restrict__ wf,
                                                const float* __restrict__ B,
                                                void* __restrict__ Y,
                                                const int* __restrict__ rmap,
                                                int ntiles) {
    const int lane = threadIdx.x & 63;
    const int gw = (blockIdx.x * blockDim.x + threadIdx.x) >> 6;
    const int nw = (gridDim.x * blockDim.x) >> 6;
    const int lm = lane & 15, quad = lane >> 4;

    bf16x8 bfr[6];
    float bias[6];
#pragma unroll
    for (int t = 0; t < 6; ++t) {
        bfr[t] = *(const bf16x8*)&wf[(t * 64 + lane) * 8];
        bias[t] = B[t * 16 + lm];
    }

    for (int tile = gw; tile < ntiles; tile += nw) {
        const long srow = (long)tile * 16 + lm;
        float4 x0 = *(const float4*)&X[srow * DIN + quad * 8];
        float4 x1 = *(const float4*)&X[srow * DIN + quad * 8 + 4];
        u32 ap[4] = {pk2(x0.x, x0.y), pk2(x0.z, x0.w), pk2(x1.x, x1.y), pk2(x1.z, x1.w)};
        bf16x8 af = *(bf16x8*)ap;
        f32x4 acc[6];
#pragma unroll
        for (int t = 0; t < 6; ++t) {
            acc[t] = (f32x4){bias[t], bias[t], bias[t], bias[t]};
            acc[t] = __builtin_amdgcn_mfma_f32_16x16x32_bf16(af, bfr[t], acc[t], 0, 0, 0);
        }
        const long rbase = (long)tile * 16 + quad * 4;
        if (POUT) {
#pragma unroll
            for (int r = 0; r < 4; ++r) {
                const long orow = SCAT ? (long)rmap[rbase + r] : rbase + r;
                if (BFOUT) {
                    u16* p = (u16*)Y + orow * DD + lm * 6;
                    *(u32*)p       = pk2(acc[0][r], acc[1][r]);
                    *(u32*)(p + 2) = pk2(acc[2][r], acc[3][r]);
                    *(u32*)(p + 4) = pk2(acc[4][r], acc[5][r]);
                } else {
                    float* p = (float*)Y + orow * DD + lm * 6;
                    *(float2*)(p)     = make_float2(acc[0][r], acc[1][r]);
                    *(float2*)(p + 2) = make_float2(acc[2][r], acc[3][r]);
                    *(float2*)(p + 4) = make_float2(acc[4][r], acc[5][r]);
                }
            }
        } else {
#pragma unroll
            for (int t = 0; t < 6; ++t) {
                const int j = t * 16 + lm;
#pragma unroll
                for (int r = 0; r < 4; ++r) {
                    float v = acc[t][r];
                    if (BFOUT) ((u16*)Y)[(rbase + r) * DD + j] = f2bf(v);
                    else       ((float*)Y)[(rbase + r) * DD + j] = v;
                }
            }
        }
    }
}

// Barrier-free MFMA 4-way node GEMM: wave w of each block handles matrix w.
// A -> f32 Ahb (3x float2). B and D interleave into DBh: row n is u16[192],
// lane-group lm owns [lm*12 .. lm*12+11] = d0..d5,b0..b5 (24 B contiguous) so
// the edge kernel gathers one 24 B segment per row instead of 2x 12 B from
// separate arrays. E -> Ehb (3x u32, as before).
__global__ __launch_bounds__(256) void k_gemm4m(const float* __restrict__ X,
                                                const u16* __restrict__ awf, const float* __restrict__ ab,
                                                const u16* __restrict__ bwf, const float* __restrict__ bb,
                                                const u16* __restrict__ dwf, const float* __restrict__ db,
                                                const u16* __restrict__ ewf, const float* __restrict__ eb,
                                                float* __restrict__ Y0, u16* __restrict__ DBh,
                                                u16* __restrict__ Y3,
                                                int ntiles) {
    const int lane = threadIdx.x & 63;
    const int w = threadIdx.x >> 6;   // matrix 0..3: A, B, D, E
    const int lm = lane & 15, quad = lane >> 4;
    const u16* wf = (w == 0) ? awf : (w == 1) ? bwf : (w == 2) ? dwf : ewf;
    const float* bp = (w == 0) ? ab : (w == 1) ? bb : (w == 2) ? db : eb;

    bf16x8 bfr[6][3];
    float bias[6];
#pragma unroll
    for (int t = 0; t < 6; ++t) {
#pragma unroll
        for (int c = 0; c < 3; ++c)
            bfr[t][c] = *(const bf16x8*)&wf[((t * 3 + c) * 64 + lane) * 8];
        bias[t] = bp[t * 16 + lm];
    }

    for (int tile = blockIdx.x; tile < ntiles; tile += gridDim.x) {
        const float* xr = X + (long)(tile * 16 + lm) * DD;
        bf16x8 a[3];
#pragma unroll
        for (int c = 0; c < 3; ++c) {
            float4 x0 = *(const float4*)&xr[c * 32 + quad * 8];
            float4 x1 = *(const float4*)&xr[c * 32 + quad * 8 + 4];
            u32 ap[4] = {pk2(x0.x, x0.y), pk2(x0.z, x0.w), pk2(x1.x, x1.y), pk2(x1.z, x1.w)};
            a[c] = *(bf16x8*)ap;
        }
        f32x4 acc[6];
#pragma unroll
        for (int t = 0; t < 6; ++t) {
            acc[t] = (f32x4){bias[t], bias[t], bias[t], bias[t]};
#pragma unroll
            for (int c = 0; c < 3; ++c)
                acc[t] = __builtin_amdgcn_mfma_f32_16x16x32_bf16(a[c], bfr[t][c], acc[t], 0, 0, 0);
        }
        const long rbase = (long)tile * 16 + quad * 4;
        if (w == 0) {
#pragma unroll
            for (int r = 0; r < 4; ++r) {
                float* p = Y0 + (rbase + r) * DD + lm * 6;
                *(float2*)(p)     = make_float2(acc[0][r], acc[1][r]);
                *(float2*)(p + 2) = make_float2(acc[2][r], acc[3][r]);
                *(float2*)(p + 4) = make_float2(acc[4][r], acc[5][r]);
            }
        } else if (w == 3) {
#pragma unroll
            for (int r = 0; r < 4; ++r) {
                u16* p = Y3 + (rbase + r) * DD + lm * 6;
                *(u32*)p       = pk2(acc[0][r], acc[1][r]);
                *(u32*)(p + 2) = pk2(acc[2][r], acc[3][r]);
                *(u32*)(p + 4) = pk2(acc[4][r], acc[5][r]);
            }
        } else {
            const int off = (w == 1) ? 6 : 0;   // B at +6, D at +0
#pragma unroll
            for (int r = 0; r < 4; ++r) {
                u16* p = DBh + (rbase + r) * 192 + lm * 12 + off;
                *(u32*)p       = pk2(acc[0][r], acc[1][r]);
                *(u32*)(p + 2) = pk2(acc[2][r], acc[3][r]);
                *(u32*)(p + 4) = pk2(acc[4][r], acc[5][r]);
            }
        }
    }
}

// Barrier-free, LDS-free, atomic-free fused edge+aggregate: one wave per node
// (grid-stride). R6 structure (VGPR<=128, srcp prefetched one chunk ahead,
// eh+cb folded into MFMA C-init) + interleaved DBh gather: 3x dwordx2 per row
// (24 B contiguous) replaces 6 dwords from two arrays -> half the gather
// instructions, ~3 cache lines per edge instead of ~4, one address chain.
__global__ __launch_bounds__(256) void k_node_edge_w(u16* ebuf,
                                                     const u16* __restrict__ cwf,  // k-permuted pack
                                                     const float* __restrict__ Cb,
                                                     const u16* __restrict__ DBh,
                                                     const u16* __restrict__ Eh,
                                                     const int* __restrict__ srcp,
                                                     const int* __restrict__ row_ptr,
                                                     const float* __restrict__ Ah,
                                                     float* __restrict__ hbuf) {
    const int lane = threadIdx.x & 63;
    const int gw = (blockIdx.x * blockDim.x + threadIdx.x) >> 6;
    const int nw = (gridDim.x * blockDim.x) >> 6;
    const int lm = lane & 15, quad = lane >> 4;

    bf16x8 bfrag[6][3];
    float cb[6];
#pragma unroll
    for (int t = 0; t < 6; ++t) {
#pragma unroll
        for (int c = 0; c < 3; ++c)
            bfrag[t][c] = *(const bf16x8*)&cwf[((t * 3 + c) * 64 + lane) * 8];
        cb[t] = Cb[t * 16 + lm];   // stored p=lm*6+t <-> actual col t*16+lm
    }

    for (int n = gw; n < NN; n += nw) {
        const int r0 = row_ptr[n], r1 = row_ptr[n + 1];
        float nacc[6] = {0.f, 0.f, 0.f, 0.f, 0.f, 0.f};
        float dacc[6] = {0.f, 0.f, 0.f, 0.f, 0.f, 0.f};

        if (r0 < r1) {
            // ehc = Cb + Eh[n] (both constant over this node's rows) -> MFMA C-init
            float ehc[6];
            {
                const u16* ep = Eh + (long)n * DD + lm * 6;
                u32 e0 = *(const u32*)ep, e1 = *(const u32*)(ep + 2), e2 = *(const u32*)(ep + 4);
                ehc[0] = cb[0] + unlo(e0); ehc[1] = cb[1] + unhi(e0);
                ehc[2] = cb[2] + unlo(e1); ehc[3] = cb[3] + unhi(e1);
                ehc[4] = cb[4] + unlo(e2); ehc[5] = cb[5] + unhi(e2);
            }
            // preload first chunk's A-fragments + srcp
            bf16x8 a[3];
            {
                const int rows = r1 - r0 < 16 ? r1 - r0 : 16;
                const long arow = r0 + (lm < rows ? lm : 0);
#pragma unroll
                for (int c = 0; c < 3; ++c)
                    a[c] = *(const bf16x8*)&ebuf[arow * DD + c * 32 + quad * 8];
            }
            int sr[4];
#pragma unroll
            for (int r = 0; r < 4; ++r) {
                const int rl = quad * 4 + r;
                sr[r] = (r0 + rl < r1) ? srcp[r0 + rl] : 0;
            }

            for (int chunk = r0; chunk < r1; chunk += 16) {
                const int rows = r1 - chunk < 16 ? r1 - chunk : 16;
                f32x4 acc[6];
#pragma unroll
                for (int t = 0; t < 6; ++t) {
                    acc[t] = (f32x4){ehc[t], ehc[t], ehc[t], ehc[t]};
#pragma unroll
                    for (int c = 0; c < 3; ++c)
                        acc[t] = __builtin_amdgcn_mfma_f32_16x16x32_bf16(a[c], bfrag[t][c], acc[t], 0, 0, 0);
                }
                // prefetch next chunk's A-fragments + srcp (consumed next iter:
                // the srcp->gather address chain moves off the critical path)
                const int nchunk = chunk + 16;
                int srn[4] = {0, 0, 0, 0};
                if (nchunk < r1) {
                    const int rows2 = r1 - nchunk < 16 ? r1 - nchunk : 16;
                    const long arow2 = nchunk + (lm < rows2 ? lm : 0);
#pragma unroll
                    for (int c = 0; c < 3; ++c)
                        a[c] = *(const bf16x8*)&ebuf[arow2 * DD + c * 32 + quad * 8];
#pragma unroll
                    for (int r = 0; r < 4; ++r) {
                        const int rl = quad * 4 + r;
                        if (nchunk + rl < r1) srn[r] = srcp[nchunk + rl];
                    }
                }
                // epilogue: row = quad*4+r; lane owns stored cols lm*6..lm*6+5
#pragma unroll
                for (int r = 0; r < 4; ++r) {
                    const int rl = quad * 4 + r;
                    if (rl < rows) {
                        const long s = sr[r];
                        const u16* dbp = DBh + s * 192 + lm * 12;
                        u16* ep = ebuf + (long)(chunk + rl) * DD + lm * 6;
                        uint2 q0 = *(const uint2*)dbp;         // d0d1 | d2d3
                        uint2 q1 = *(const uint2*)(dbp + 4);   // d4d5 | b0b1
                        uint2 q2 = *(const uint2*)(dbp + 8);   // b2b3 | b4b5
                        u32 o0 = *(const u32*)ep, o1 = *(const u32*)(ep + 2), o2 = *(const u32*)(ep + 4);
                        float dh[6] = {unlo(q0.x), unhi(q0.x), unlo(q0.y), unhi(q0.y), unlo(q1.x), unhi(q1.x)};
                        float bh[6] = {unlo(q1.y), unhi(q1.y), unlo(q2.x), unhi(q2.x), unlo(q2.y), unhi(q2.y)};
                        float od[6] = {unlo(o0), unhi(o0), unlo(o1), unhi(o1), unlo(o2), unhi(o2)};
                        float ov[6];
#pragma unroll
                        for (int t = 0; t < 6; ++t) {
                            float en = acc[t][r] + dh[t];
                            float sg = frcp(1.f + __expf(-en));
                            nacc[t] += bh[t] * sg;
                            dacc[t] += sg;
                            ov[t] = od[t] + fmaxf(en, 0.f);
                        }
                        *(u32*)ep       = pk2(ov[0], ov[1]);
                        *(u32*)(ep + 2) = pk2(ov[2], ov[3]);
                        *(u32*)(ep + 4) = pk2(ov[4], ov[5]);
                    }
                }
#pragma unroll
                for (int r = 0; r < 4; ++r) sr[r] = srn[r];
            }
        }
        // reduce over quads (butterfly across lane bits 4-5)
#pragma unroll
        for (int t = 0; t < 6; ++t) {
            float x = nacc[t], y = dacc[t];
            x += __shfl_xor(x, 16); y += __shfl_xor(y, 16);
            x += __shfl_xor(x, 32); y += __shfl_xor(y, 32);
            nacc[t] = x; dacc[t] = y;
        }
        if (quad == 0) {
            const float* ap = Ah + (long)n * DD + lm * 6;
            float* hp = hbuf + (long)n * DD + lm * 6;
            float val[6];
#pragma unroll
            for (int t = 0; t < 6; ++t)
                val[t] = fmaxf(ap[t] + nacc[t] * frcp(dacc[t] + EPSF), 0.f);
            float2 h0 = *(float2*)hp, h1 = *(float2*)(hp + 2), h2 = *(float2*)(hp + 4);
            *(float2*)(hp)     = make_float2(h0.x + val[0], h0.y + val[1]);
            *(float2*)(hp + 2) = make_float2(h1.x + val[2], h1.y + val[3]);
            *(float2*)(hp + 4) = make_float2(h2.x + val[4], h2.y + val[5]);
        }
    }
}

// small MLP stage, one thread per output element
__global__ void k_mlp(const float* __restrict__ X, const float* __restrict__ W,
                      const float* __restrict__ B, float* __restrict__ Y,
                      int K, int Dout, int act, long total) {
    long idx = (long)blockIdx.x * blockDim.x + threadIdx.x;
    if (idx >= total) return;
    int row = (int)(idx / Dout);
    int j = (int)(idx - (long)row * Dout);
    const float* xr = X + (long)row * K;
    float acc = B[j];
    for (int k = 0; k < K; ++k) acc = fmaf(xr[k], W[k * Dout + j], acc);
    if (act == 1) acc = fmaxf(acc, 0.f);
    else if (act == 2) acc = frcp(1.f + __expf(-acc));
    Y[idx] = acc;
}

extern "C" void kernel_launch(void* const* d_in, const int* in_sizes, int n_in,
                              void* d_out, int out_size, void* d_ws, size_t ws_size,
                              hipStream_t stream) {
    const float* h_in = (const float*)d_in[0];
    const float* e_in = (const float*)d_in[1];
    const int* src = (const int*)d_in[2];
    const int* dst = (const int*)d_in[3];
    const float* fp_w = (const float*)d_in[4];
    const float* fp_b = (const float*)d_in[5];
    const float* ep_w = (const float*)d_in[6];
    const float* ep_b = (const float*)d_in[7];
    const float* A_w = (const float*)d_in[8];
    const float* A_b = (const float*)d_in[9];
    const float* B_w = (const float*)d_in[10];
    const float* B_b = (const float*)d_in[11];
    const float* C_w = (const float*)d_in[12];
    const float* C_b = (const float*)d_in[13];
    const float* D_w = (const float*)d_in[14];
    const float* D_b = (const float*)d_in[15];
    const float* E_w = (const float*)d_in[16];
    const float* E_b = (const float*)d_in[17];
    const float* mlp0_w = (const float*)d_in[18];
    const float* mlp0_b = (const float*)d_in[19];
    const float* mlp1_w = (const float*)d_in[20];
    const float* mlp1_b = (const float*)d_in[21];
    const float* mlp2_w = (const float*)d_in[22];
    const float* mlp2_b = (const float*)d_in[23];
    float* out = (float*)d_out;

    const size_t ND_ = (size_t)NN * DD;
    const size_t ED_ = (size_t)NE * DD;
    const size_t FRAG = (size_t)NL * 6 * 3 * 64 * 8;   // u16 count per packed tensor
    char* w = (char*)d_ws;
    float* hbuf = (float*)w; w += ND_ * 4;
    float* Ahb  = (float*)w; w += ND_ * 4;
    u16* DBhb = (u16*)w; w += (size_t)NN * 192 * 2;   // interleaved D|B rows
    u16* Ehb  = (u16*)w; w += ND_ * 2;
    u16* ebuf = (u16*)w; w += ED_ * 2;
    int* counts  = (int*)w; w += (size_t)NN * 4;
    int* cursor  = (int*)w; w += (size_t)NN * 4;
    int* row_ptr = (int*)w; w += (size_t)(NN + 1) * 4 + 12;
    int* bsum    = (int*)w; w += 256;
    int* inv     = (int*)w; w += (size_t)NE * 4;
    int* srcp    = (int*)w; w += (size_t)NE * 4;
    u16* awf = (u16*)w; w += FRAG * 2;
    u16* bwf = (u16*)w; w += FRAG * 2;
    u16* cwf = (u16*)w; w += FRAG * 2;
    u16* dwf = (u16*)w; w += FRAG * 2;
    u16* ewf = (u16*)w; w += FRAG * 2;
    u16* wfp = (u16*)w; w += (size_t)6 * 64 * 8 * 2;
    u16* wep = (u16*)w; w += (size_t)6 * 64 * 8 * 2;
    float* w0p = (float*)w; w += (size_t)DD * 48 * 4;
    size_t need = (size_t)(w - (char*)d_ws);
    if (ws_size < need) return;  // uniform -> graph-safe; fails absmax as diagnostic

    // CSR build (dst-sorted edge permutation), multi-block scan
    k_zero4<<<(NN / 4 + 255) / 256, 256, 0, stream>>>(counts, NN / 4);
    k_hist<<<(NE + 255) / 256, 256, 0, stream>>>(dst, counts);
    const int nsb = (NN + 1023) / 1024;
    k_scan1<<<nsb, 1024, 0, stream>>>(counts, row_ptr, bsum, NN);
    k_scan2<<<1, 64, 0, stream>>>(bsum, nsb);
    k_scan3<<<(NN + 255) / 256, 256, 0, stream>>>(row_ptr, cursor, bsum, NN);
    k_scatter<<<(NE + 255) / 256, 256, 0, stream>>>(src, dst, cursor, inv, srcp);

    // fused weight packing (all layer weights k-permuted; projections canonical)
    const int packTot = 5 * (NL * 6 * 3 * 64) + 768 + DD * 48;
    k_packAll<<<(packTot + 255) / 256, 256, 0, stream>>>(A_w, B_w, C_w, D_w, E_w,
                                                         fp_w, ep_w, mlp0_w,
                                                         awf, bwf, cwf, dwf, ewf,
                                                         wfp, wep, w0p);

    // input projections: h sequential->f32 permuted-basis; e sequential read,
    // scatter-write (dst-sorted position via inv), bf16 permuted-basis
    k_proj_m<false, true, false><<<256, 256, 0, stream>>>(h_in, wfp, fp_b, hbuf, nullptr, NN / 16);
    k_proj_m<true, true, true><<<2048, 256, 0, stream>>>(e_in, wep, ep_b, ebuf, inv, NE / 16);

    const size_t LFRAG = (size_t)6 * 3 * 64 * 8;
    for (int l = 0; l < NL; ++l) {
        const float* Ab = A_b + (size_t)l * DD;
        const float* Bb = B_b + (size_t)l * DD;
        const float* Cb = C_b + (size_t)l * DD;
        const float* Db = D_b + (size_t)l * DD;
        const float* Eb = E_b + (size_t)l * DD;

        k_gemm4m<<<1280, 256, 0, stream>>>(hbuf,
                                           awf + l * LFRAG, Ab, bwf + l * LFRAG, Bb,
                                           dwf + l * LFRAG, Db, ewf + l * LFRAG, Eb,
                                           Ahb, DBhb, Ehb, NN / 16);
        k_node_edge_w<<<2560, 256, 0, stream>>>(ebuf, cwf + l * LFRAG, Cb, DBhb, Ehb,
                                                srcp, row_ptr, Ahb, hbuf);
    }

    // MLP readout: 96 -> 48 (relu) -> 24 (relu) -> 10 (sigmoid). Reuse Ahb as temps.
    // Stage 0 uses the permuted-row weight copy (hbuf is in permuted basis).
    float* y1 = Ahb;
    float* y2 = Ahb + (size_t)NN * 48;
    long t0 = (long)NN * 48, t1 = (long)NN * 24, t2 = (long)NN * NCLS;
    k_mlp<<<(int)((t0 + 255) / 256), 256, 0, stream>>>(hbuf, w0p, mlp0_b, y1, DD, 48, 1, t0);
    k_mlp<<<(int)((t1 + 255) / 256), 256, 0, stream>>>(y1, mlp1_w, mlp1_b, y2, 48, 24, 1, t1);
    k_mlp<<<(int)((t2 + 255) / 256), 256, 0, stream>>>(y2, mlp2_w, mlp2_b, out, 24, NCLS, 2, t2);
}